// Round 12
// baseline (692.532 us; speedup 1.0000x reference)
//
#include <hip/hip_runtime.h>
#include <math.h>

// TVKoopmanMoE: B=4096, C=128, D=32, K=8, R=8, NSEG=3, STEPS=8 each, DT=0.1
//  - kA: gates w (softmax) + diag^2
//  - AS GEMM via MFMA bf16 hi/lo split (kCvtA/kCvtB/kB3), bias folded via K-ext
//  - kL3: Ltil GEMM via MFMA hi/lo; kLLT: AS -= Ltil Ltil^T (unchanged)
//  - kC11: ONE WAVE per b expm+propagation. R11's kC10 with the PROPAGATION
//    LOOP fully register-resident: cov/T1 B-frags built from C/D registers via
//    hh-half shfl_xor(32) (no LDS, no barriers); Qd hoisted to regs; z in a
//    register with shfl broadcast. Taylor/squarings/Qd unchanged.

#define NSEGC 3
#define BSZ   4096
#define MUC   0.14861455999447191f   /* -ln(0.7)/(0.1*24) */
#define XSC   0.025f                 /* DT / 2^SQ = 0.1/4 */
#define XRS(r) (((r) & 7) << 2)

typedef unsigned short ushort_t;
typedef unsigned int uint_t;
typedef __attribute__((ext_vector_type(8))) short bf16x8;
typedef __attribute__((ext_vector_type(16))) float f32x16;

__device__ __forceinline__ void ld4(float d[4], const float* p) {
  const float4 v = *(const float4*)p; d[0]=v.x; d[1]=v.y; d[2]=v.z; d[3]=v.w;
}
__device__ __forceinline__ void st4(float* p, const float d[4]) {
  *(float4*)p = make_float4(d[0], d[1], d[2], d[3]);
}
__device__ __forceinline__ unsigned short bf_rne(float x) {
  unsigned b = __float_as_uint(x);
  unsigned r = b + 0x7FFFu + ((b >> 16) & 1u);
  return (unsigned short)(r >> 16);
}
__device__ __forceinline__ float bf2f(short v) {
  return __uint_as_float(((uint_t)(unsigned short)v) << 16);
}

// ---------------- kA: gates (softmax(logits/2)) and diag^2 ----------------
__global__ __launch_bounds__(64) void kA(const float* __restrict__ ctx,
    const float* __restrict__ GW, const float* __restrict__ Gb,
    const float* __restrict__ SgW, const float* __restrict__ Sgb,
    float* __restrict__ Wsm, float* __restrict__ Q2) {
  const int b = blockIdx.x, s = blockIdx.y, l = threadIdx.x;
  __shared__ float c[128];
  c[l]      = ctx[(size_t)b*128 + l];
  c[l + 64] = ctx[(size_t)b*128 + 64 + l];
  __syncthreads();
  if (l < 8) {
    float acc = Gb[s*8 + l];
    #pragma unroll 4
    for (int q = 0; q < 128; ++q) acc += c[q] * GW[(size_t)(s*128 + q)*8 + l];
    float li = acc * 0.5f;            // / TEMP (=2)
    float m = li;
    m = fmaxf(m, __shfl_xor(m, 1));
    m = fmaxf(m, __shfl_xor(m, 2));
    m = fmaxf(m, __shfl_xor(m, 4));
    float e = expf(li - m);
    float sum = e;
    sum += __shfl_xor(sum, 1);
    sum += __shfl_xor(sum, 2);
    sum += __shfl_xor(sum, 4);
    Wsm[((size_t)s*BSZ + b)*8 + l] = e / sum;
  } else if (l < 40) {
    const int d = l - 8;
    float acc = Sgb[s*32 + d];
    #pragma unroll 4
    for (int q = 0; q < 128; ++q) acc += c[q] * SgW[(size_t)(s*128 + q)*32 + d];
    float sp = fmaxf(acc, 0.f) + log1pf(expf(-fabsf(acc)));  // stable softplus
    float dg = fminf(sp, 1.0f);
    Q2[((size_t)s*BSZ + b)*32 + d] = dg * dg;
  }
}

// -------- kCvtX: ctx -> hi/lo bf16 panels [4096][128] ----------------------
__global__ __launch_bounds__(256) void kCvtX(const float* __restrict__ ctx,
    ushort_t* __restrict__ Xh, ushort_t* __restrict__ Xl) {
  const int idx = blockIdx.x*256 + threadIdx.x;
  const float v = ctx[idx];
  const unsigned short h = bf_rne(v);
  Xh[idx] = h;
  Xl[idx] = bf_rne(v - __uint_as_float(((unsigned)h) << 16));
}

// -------- kCvtL: lwT[s][n][c] = L_W[s][c][n] hi/lo bf16 --------------------
__global__ __launch_bounds__(256) void kCvtL(const float* __restrict__ LW,
    ushort_t* __restrict__ Lh, ushort_t* __restrict__ Ll) {
  __shared__ float tile[32][33];
  const int nb = blockIdx.x * 32, cb = blockIdx.y * 32, s = blockIdx.z;
  const int tx = threadIdx.x & 31, ty = threadIdx.x >> 5;
  for (int r = ty; r < 32; r += 8)
    tile[r][tx] = LW[((size_t)(s*128 + cb + r))*2048 + nb + tx];
  __syncthreads();
  for (int r = ty; r < 32; r += 8) {
    const float v = tile[tx][r];          // LW[cb+tx][nb+r]
    const unsigned short h = bf_rne(v);
    const size_t o = ((size_t)s*2048 + nb + r)*128 + cb + tx;
    Lh[o] = h;
    Ll[o] = bf_rne(v - __uint_as_float(((unsigned)h) << 16));
  }
}

// -------- kCvtA: A'[b][kc] hi/lo bf16; kc<1024: w[k]*ctx[c]; 1024..1031: w; pad 0
__global__ __launch_bounds__(256) void kCvtA(const float* __restrict__ ctx,
    const float* __restrict__ Wsm, ushort_t* __restrict__ Ah,
    ushort_t* __restrict__ Al, int s) {
  __shared__ float cs[128];
  __shared__ float wwv[8];
  const int b = blockIdx.x, t = threadIdx.x;
  if (t < 128) cs[t] = ctx[(size_t)b*128 + t];
  else if (t < 136) wwv[t - 128] = Wsm[((size_t)s*BSZ + b)*8 + (t - 128)];
  __syncthreads();
  for (int kc = t; kc < 1088; kc += 256) {
    float v = 0.f;
    if (kc < 1024) v = wwv[kc >> 7] * cs[kc & 127];
    else if (kc < 1032) v = wwv[kc - 1024];
    const unsigned short h = bf_rne(v);
    const float hf = __uint_as_float(((unsigned)h) << 16);
    Ah[(size_t)b*1088 + kc] = h;
    Al[(size_t)b*1088 + kc] = bf_rne(v - hf);
  }
}

// -------- kCvtB: B'[s][n][kc] = V2^T hi/lo bf16 (all 3 segments) -----------
__global__ __launch_bounds__(256) void kCvtB(const float* __restrict__ SW,
    const float* __restrict__ Sb, ushort_t* __restrict__ Bh,
    ushort_t* __restrict__ Bl) {
  const int n = blockIdx.x, s = blockIdx.y, t = threadIdx.x;
  const int i = n >> 5, j = n & 31, nT = j*32 + i;
  ushort_t* bh = Bh + (size_t)s*1114112;
  ushort_t* bl = Bl + (size_t)s*1114112;
  for (int kc = t; kc < 1088; kc += 256) {
    float v = 0.f;
    if (kc < 1024) {
      const int k = kc >> 7, c = kc & 127;
      const float* base = SW + ((size_t)(s*128 + c))*8192 + (size_t)k*1024;
      v = base[n] - base[nT];
    } else if (kc < 1032) {
      const int k = kc - 1024;
      const float* base = Sb + (size_t)s*8192 + (size_t)k*1024;
      v = base[n] - base[nT];
    }
    const unsigned short h = bf_rne(v);
    const float hf = __uint_as_float(((unsigned)h) << 16);
    bh[(size_t)n*1088 + kc] = h;
    bl[(size_t)n*1088 + kc] = bf_rne(v - hf);
  }
}

// -------- kB3: AS_seg = A' @ B'^T via 32x32x16 bf16 MFMA, 3-product hi/lo ----
__global__ __launch_bounds__(256) void kB3(const ushort_t* __restrict__ Ah,
    const ushort_t* __restrict__ Al, const ushort_t* __restrict__ Bh,
    const ushort_t* __restrict__ Bl, float* __restrict__ ASseg) {
  __shared__ ushort_t sArr[2][2][8192];   // [buf][A/B][128 rows x 64 cols]
  const int t = threadIdx.x;
  const int l = t & 63, w = t >> 6;
  const int hh = l >> 5, lane31 = l & 31;
  const int nb = blockIdx.x * 128, bb = blockIdx.y * 128;
  const int wr0 = (w & 1) * 64, wc0 = (w >> 1) * 64;

  const ushort_t* APT[3] = {Ah, Ah, Al};
  const ushort_t* BPT[3] = {Bh, Bl, Bh};

  f32x16 acc[2][2];
  #pragma unroll
  for (int a = 0; a < 2; ++a)
    #pragma unroll
    for (int bq = 0; bq < 2; ++bq)
      #pragma unroll
      for (int e = 0; e < 16; ++e) acc[a][bq][e] = 0.f;

  #define STAGE(buf, it) do {                                                  \
    const int p_ = (it) / 17, ks_ = (it) - p_*17;                              \
    const ushort_t* As_ = APT[p_];                                             \
    const ushort_t* Bs_ = BPT[p_];                                             \
    _Pragma("unroll")                                                          \
    for (int i_ = 0; i_ < 4; ++i_) {                                           \
      const int gidx_ = i_*256 + t;                                            \
      const int r_ = gidx_ >> 3, g_ = gidx_ & 7;                               \
      const int gs_ = g_ ^ (r_ & 7);                                           \
      const ushort_t* srcA_ = As_ + (size_t)(bb + r_)*1088 + ks_*64 + gs_*8;   \
      const ushort_t* srcB_ = Bs_ + (size_t)(nb + r_)*1088 + ks_*64 + gs_*8;   \
      __builtin_amdgcn_global_load_lds(                                        \
        (const __attribute__((address_space(1))) unsigned int*)srcA_,          \
        (__attribute__((address_space(3))) unsigned int*)&sArr[buf][0][(i_*256 + w*64)*8], \
        16, 0, 0);                                                             \
      __builtin_amdgcn_global_load_lds(                                        \
        (const __attribute__((address_space(1))) unsigned int*)srcB_,          \
        (__attribute__((address_space(3))) unsigned int*)&sArr[buf][1][(i_*256 + w*64)*8], \
        16, 0, 0);                                                             \
    }                                                                          \
  } while (0)

  STAGE(0, 0);
  int cur = 0;
  #pragma unroll 1
  for (int it = 0; it < 51; ++it) {
    __syncthreads();                      // drain loads into buf[cur]
    if (it + 1 < 51) STAGE(cur ^ 1, it + 1);
    const ushort_t* lA = &sArr[cur][0][0];
    const ushort_t* lB = &sArr[cur][1][0];
    #pragma unroll
    for (int kc = 0; kc < 4; ++kc) {
      bf16x8 af[2], bfr[2];
      #pragma unroll
      for (int rt = 0; rt < 2; ++rt) {
        const int row = wr0 + rt*32 + lane31;
        const int slot = (kc*2 + hh) ^ (row & 7);
        af[rt] = *(const bf16x8*)&lA[row*64 + slot*8];
      }
      #pragma unroll
      for (int ct = 0; ct < 2; ++ct) {
        const int row = wc0 + ct*32 + lane31;
        const int slot = (kc*2 + hh) ^ (row & 7);
        bfr[ct] = *(const bf16x8*)&lB[row*64 + slot*8];
      }
      #pragma unroll
      for (int rt = 0; rt < 2; ++rt)
        #pragma unroll
        for (int ct = 0; ct < 2; ++ct)
          acc[rt][ct] = __builtin_amdgcn_mfma_f32_32x32x16_bf16(
              af[rt], bfr[ct], acc[rt][ct], 0, 0, 0);
    }
    cur ^= 1;
  }
  #undef STAGE

  #pragma unroll
  for (int rt = 0; rt < 2; ++rt)
    #pragma unroll
    for (int ct = 0; ct < 2; ++ct) {
      float* o = ASseg + ((size_t)(bb + wr0 + rt*32))*1024 + nb + wc0 + ct*32 + lane31;
      #pragma unroll
      for (int reg = 0; reg < 16; ++reg) {
        const int row = (reg & 3) + 8*(reg >> 2) + 4*hh;
        o[(size_t)row*1024] = acc[rt][ct][reg];
      }
    }
}

// -------- kL3: lt = (ctx @ L_W + Lb)*sqrt(w) via MFMA hi/lo (K=128) --------
__global__ __launch_bounds__(256) void kL3(const ushort_t* __restrict__ Xh,
    const ushort_t* __restrict__ Xl, const ushort_t* __restrict__ Lh,
    const ushort_t* __restrict__ Ll, const float* __restrict__ Lb,
    const float* __restrict__ Wsm, float* __restrict__ lt, int s) {
  __shared__ ushort_t sArr[2][2][8192];
  __shared__ float sqw[128][8];
  const int t = threadIdx.x;
  const int l = t & 63, w = t >> 6;
  const int hh = l >> 5, lane31 = l & 31;
  const int nb = blockIdx.x * 128, bb = blockIdx.y * 128;
  const int wr0 = (w & 1) * 64, wc0 = (w >> 1) * 64;
  for (int i = t; i < 1024; i += 256)
    sqw[i >> 3][i & 7] = sqrtf(Wsm[((size_t)s*BSZ + bb + (i >> 3))*8 + (i & 7)]);

  const ushort_t* APT[3] = {Xh, Xh, Xl};
  const ushort_t* BPT[3] = {Lh + (size_t)s*262144, Ll + (size_t)s*262144,
                            Lh + (size_t)s*262144};

  f32x16 acc[2][2];
  #pragma unroll
  for (int a = 0; a < 2; ++a)
    #pragma unroll
    for (int bq = 0; bq < 2; ++bq)
      #pragma unroll
      for (int e = 0; e < 16; ++e) acc[a][bq][e] = 0.f;

  #define STAGEL(buf, it) do {                                                 \
    const int p_ = (it) >> 1, ks_ = (it) & 1;                                  \
    const ushort_t* As_ = APT[p_];                                             \
    const ushort_t* Bs_ = BPT[p_];                                             \
    _Pragma("unroll")                                                          \
    for (int i_ = 0; i_ < 4; ++i_) {                                           \
      const int gidx_ = i_*256 + t;                                            \
      const int r_ = gidx_ >> 3, g_ = gidx_ & 7;                               \
      const int gs_ = g_ ^ (r_ & 7);                                           \
      const ushort_t* srcA_ = As_ + (size_t)(bb + r_)*128 + ks_*64 + gs_*8;    \
      const ushort_t* srcB_ = Bs_ + (size_t)(nb + r_)*128 + ks_*64 + gs_*8;    \
      __builtin_amdgcn_global_load_lds(                                        \
        (const __attribute__((address_space(1))) unsigned int*)srcA_,          \
        (__attribute__((address_space(3))) unsigned int*)&sArr[buf][0][(i_*256 + w*64)*8], \
        16, 0, 0);                                                             \
      __builtin_amdgcn_global_load_lds(                                        \
        (const __attribute__((address_space(1))) unsigned int*)srcB_,          \
        (__attribute__((address_space(3))) unsigned int*)&sArr[buf][1][(i_*256 + w*64)*8], \
        16, 0, 0);                                                             \
    }                                                                          \
  } while (0)

  STAGEL(0, 0);
  int cur = 0;
  #pragma unroll 1
  for (int it = 0; it < 6; ++it) {
    __syncthreads();
    if (it + 1 < 6) STAGEL(cur ^ 1, it + 1);
    const ushort_t* lA = &sArr[cur][0][0];
    const ushort_t* lB = &sArr[cur][1][0];
    #pragma unroll
    for (int kc = 0; kc < 4; ++kc) {
      bf16x8 af[2], bfr[2];
      #pragma unroll
      for (int rt = 0; rt < 2; ++rt) {
        const int row = wr0 + rt*32 + lane31;
        const int slot = (kc*2 + hh) ^ (row & 7);
        af[rt] = *(const bf16x8*)&lA[row*64 + slot*8];
      }
      #pragma unroll
      for (int ct = 0; ct < 2; ++ct) {
        const int row = wc0 + ct*32 + lane31;
        const int slot = (kc*2 + hh) ^ (row & 7);
        bfr[ct] = *(const bf16x8*)&lB[row*64 + slot*8];
      }
      #pragma unroll
      for (int rt = 0; rt < 2; ++rt)
        #pragma unroll
        for (int ct = 0; ct < 2; ++ct)
          acc[rt][ct] = __builtin_amdgcn_mfma_f32_32x32x16_bf16(
              af[rt], bfr[ct], acc[rt][ct], 0, 0, 0);
    }
    cur ^= 1;
  }
  #undef STAGEL

  // epilogue: (acc + Lb[n]) * sqrt(w[b][n>>8]) -> lt[b][ltcol(n)]
  #pragma unroll
  for (int rt = 0; rt < 2; ++rt)
    #pragma unroll
    for (int ct = 0; ct < 2; ++ct) {
      const int n = nb + wc0 + ct*32 + lane31;
      const float lb = Lb[(size_t)s*2048 + n];
      const int kidx = n >> 8;
      const int ltcol = (kidx << 8) + ((n & 7) << 5) + ((n >> 3) & 31);
      #pragma unroll
      for (int reg = 0; reg < 16; ++reg) {
        const int lrow = wr0 + rt*32 + (reg & 3) + 8*(reg >> 2) + 4*hh;
        lt[(size_t)(bb + lrow)*2048 + ltcol] =
            (acc[rt][ct][reg] + lb) * sqw[lrow][kidx];
      }
    }
}

// ---------------- kLLT: AS -= Ltil Ltil^T  (4 b per block) ----------------
__global__ __launch_bounds__(128) void kLLT(const float* __restrict__ LT,
                                            float* __restrict__ AS, int s) {
  __shared__ float L4[4][64][32];
  const int t = threadIdx.x;
  const int bbase = blockIdx.x * 4;
  {
    float* l4f = &L4[0][0][0];
    const float* src = LT + (size_t)bbase * 2048;
    for (int i = t*4; i < 8192; i += 512)
      *(float4*)&l4f[i] = *(const float4*)&src[i];
  }
  __syncthreads();
  const int b = t >> 5, u = t & 31;
  const int i0 = (u >> 2) * 4, j0 = (u & 3) * 8;
  float acc[4][8] = {};
  #pragma unroll 8
  for (int kr = 0; kr < 64; ++kr) {
    float pa[4], pb[8];
    ld4(pa, &L4[b][kr][i0]);
    ld4(pb, &L4[b][kr][j0]); ld4(pb + 4, &L4[b][kr][j0 + 4]);
    #pragma unroll
    for (int ii = 0; ii < 4; ++ii)
      #pragma unroll
      for (int jj = 0; jj < 8; ++jj) acc[ii][jj] += pa[ii] * pb[jj];
  }
  float* dst = AS + ((size_t)s*BSZ + bbase + b)*1024;
  for (int ii = 0; ii < 4; ++ii) {
    float x[8];
    ld4(x, &dst[(i0+ii)*32 + j0]); ld4(x + 4, &dst[(i0+ii)*32 + j0 + 4]);
    #pragma unroll
    for (int jj = 0; jj < 8; ++jj) x[jj] -= acc[ii][jj];
    st4(&dst[(i0+ii)*32 + j0], x); st4(&dst[(i0+ii)*32 + j0 + 4], &x[4]);
  }
}

// ================= kC11: MFMA hi/lo expm + register-resident propagation ======
struct Frag { bf16x8 h0, l0, h1, l1; };

__device__ __forceinline__ void cvt8(const float x[8], bf16x8& hi, bf16x8& lo) {
  uint_t h[4], l[4];
  #pragma unroll
  for (int p = 0; p < 4; ++p) {
    const uint_t b0 = __float_as_uint(x[2*p]);
    const uint_t b1 = __float_as_uint(x[2*p + 1]);
    h[p] = __builtin_amdgcn_perm(b1, b0, 0x07060302u);
    const float l0f = x[2*p]     - __uint_as_float(b0 & 0xFFFF0000u);  // exact
    const float l1f = x[2*p + 1] - __uint_as_float(b1 & 0xFFFF0000u);  // exact
    l[p] = __builtin_amdgcn_perm(__float_as_uint(l1f), __float_as_uint(l0f),
                                 0x07060302u);
  }
  hi = __builtin_bit_cast(bf16x8, make_uint4(h[0], h[1], h[2], h[3]));
  lo = __builtin_bit_cast(bf16x8, make_uint4(l[0], l[1], l[2], l[3]));
}
__device__ __forceinline__ void rd_row8(const float* M, int r, int kb, float o[8]) {
  const float* p = M + r*32;
  ld4(o,     p + ((kb)     ^ XRS(r)));
  ld4(o + 4, p + ((kb + 4) ^ XRS(r)));
}
__device__ __forceinline__ void rd_col8(const float* M, int c, int kb, float o[8]) {
  #pragma unroll
  for (int e = 0; e < 8; ++e) o[e] = M[(kb + e)*32 + (c ^ XRS(kb + e))];
}
__device__ __forceinline__ void mkfrag_row(const float* M, int r, int hoff, Frag& f) {
  float t0[8], t1[8];
  rd_row8(M, r, hoff, t0);
  rd_row8(M, r, 16 + hoff, t1);
  cvt8(t0, f.h0, f.l0);
  cvt8(t1, f.h1, f.l1);
}
__device__ __forceinline__ void mkfrag_col(const float* M, int c, int hoff, Frag& f) {
  float t0[8], t1[8];
  rd_col8(M, c, hoff, t0);
  rd_col8(M, c, 16 + hoff, t1);
  cvt8(t0, f.h0, f.l0);
  cvt8(t1, f.h1, f.l1);
}
// Build frag with element value X[16c+8h+e][j] from X's C/D registers
// (lane (j,h) reg r = X[(r&3)+8*(r>>2)+4h][j]) via hh-half exchange.
// = B-frag of X^T; = A-frag of X when X is symmetric.
__device__ __forceinline__ void frag_from_cd(const float X[16], int hh, Frag& f) {
  #pragma unroll
  for (int c = 0; c < 2; ++c) {
    float sw[8];
    #pragma unroll
    for (int q = 0; q < 8; ++q) sw[q] = __shfl_xor(X[8*c + q], 32);
    float bv[8];
    #pragma unroll
    for (int e = 0; e < 4; ++e) {
      bv[e]     = (hh == 0) ? X[8*c + e]     : sw[4 + e];
      bv[e + 4] = (hh == 0) ? sw[e]          : X[8*c + e + 4];
    }
    if (c == 0) cvt8(bv, f.h0, f.l0);
    else        cvt8(bv, f.h1, f.l1);
  }
}
__device__ __forceinline__ f32x16 mmacc(const Frag& A, const Frag& B, f32x16 acc) {
  acc = __builtin_amdgcn_mfma_f32_32x32x16_bf16(A.h0, B.h0, acc, 0, 0, 0);
  acc = __builtin_amdgcn_mfma_f32_32x32x16_bf16(A.h0, B.l0, acc, 0, 0, 0);
  acc = __builtin_amdgcn_mfma_f32_32x32x16_bf16(A.l0, B.h0, acc, 0, 0, 0);
  acc = __builtin_amdgcn_mfma_f32_32x32x16_bf16(A.h1, B.h1, acc, 0, 0, 0);
  acc = __builtin_amdgcn_mfma_f32_32x32x16_bf16(A.h1, B.l1, acc, 0, 0, 0);
  acc = __builtin_amdgcn_mfma_f32_32x32x16_bf16(A.l1, B.h1, acc, 0, 0, 0);
  return acc;
}
__device__ __forceinline__ f32x16 zero16() {
  f32x16 z = {0.f,0.f,0.f,0.f,0.f,0.f,0.f,0.f,0.f,0.f,0.f,0.f,0.f,0.f,0.f,0.f};
  return z;
}
__device__ __forceinline__ void st_T(float* M, int j, int ho4, const float v[16]) {
  float* p = M + j*32;
  #pragma unroll
  for (int m = 0; m < 4; ++m) st4(p + ((8*m + ho4) ^ XRS(j)), v + 4*m);
}
__device__ __forceinline__ void ld16_T(const float* M, int j, int ho4, float o[16]) {
  const float* p = M + j*32;
  #pragma unroll
  for (int m = 0; m < 4; ++m) ld4(o + 4*m, p + ((8*m + ho4) ^ XRS(j)));
}

__global__ __launch_bounds__(64, 3) void kC11(const float* __restrict__ AS,
    const float* __restrict__ Q2, const float* __restrict__ z0,
    float* __restrict__ out) {
  __shared__ float S11[1024];  // R11^T (Phi^T)
  __shared__ float S12[1024];  // a staging; R12^T (E12^T)
  __shared__ float S22[1024];  // R22^T ; later Qd
  __shared__ float qds[32];
  const int b = blockIdx.x, t = threadIdx.x;
  const int j = t & 31, hh = t >> 5;
  const int hoff = hh * 8, ho4 = hh * 4;

  float zj = z0[(size_t)b*32 + j];   // z[j], replicated across halves
  float covreg[16];
  #pragma unroll
  for (int r = 0; r < 16; ++r) covreg[r] = 0.f;

  float* covout = out + 3145728 + (size_t)b*24576;
  float* stout  = out + (size_t)b*768;

  for (int s = 0; s < NSEGC; ++s) {
    // ---------- init: load A, -muI, frob clamp, scale; stage a via S12 -------
    if (t < 32) qds[t] = Q2[((size_t)s*BSZ + b)*32 + t] * XSC;
    const float* asb = AS + ((size_t)s*BSZ + b)*1024;
    float av[16];
    #pragma unroll
    for (int m = 0; m < 4; ++m) ld4(av + 4*m, &asb[j*32 + 16*hh + 4*m]);
    #pragma unroll
    for (int i = 0; i < 16; ++i) if (16*hh + i == j) av[i] -= MUC;
    float ssq = 0.f;
    #pragma unroll
    for (int i = 0; i < 16; ++i) ssq += av[i]*av[i];
    #pragma unroll
    for (int off = 1; off < 64; off <<= 1) ssq += __shfl_xor(ssq, off);
    const float frob = sqrtf(ssq);
    const float sc = (frob > 3.0f ? 3.0f / (frob + 1e-6f) : 1.0f) * XSC;
    #pragma unroll
    for (int i = 0; i < 16; ++i) av[i] *= sc;
    __syncthreads();
    #pragma unroll
    for (int m = 0; m < 4; ++m)
      st4(&S12[j*32 + ((16*hh + 4*m) ^ XRS(j))], av + 4*m);  // S12 = a (rows)
    __syncthreads();
    Frag aA, aT;
    mkfrag_row(S12, j, hoff, aA);   // A-frag of a
    mkfrag_col(S12, j, hoff, aT);   // A-frag of a^T
    __syncthreads();
    #pragma unroll
    for (int m = 0; m < 4; ++m) {
      float id[4], zo[4] = {0.f, 0.f, 0.f, 0.f};
      #pragma unroll
      for (int e = 0; e < 4; ++e) id[e] = (16*hh + 4*m + e == j) ? 1.f : 0.f;
      st4(&S11[j*32 + ((16*hh + 4*m) ^ XRS(j))], id);
      st4(&S22[j*32 + ((16*hh + 4*m) ^ XRS(j))], id);
      st4(&S12[j*32 + ((16*hh + 4*m) ^ XRS(j))], zo);
    }
    __syncthreads();
    float qv[16];
    #pragma unroll
    for (int r = 0; r < 16; ++r) qv[r] = qds[(r&3) + 8*(r>>2) + ho4];

    // ---------- Taylor Horner ORDER=5 on X=[[a,q],[0,-a^T]] (transposed blocks)
    for (int k = 5; k >= 1; --k) {
      const float rk = 1.0f / (float)k;
      Frag Bf;
      float Xs[16];
      mkfrag_row(S11, j, hoff, Bf);
      f32x16 X = mmacc(aA, Bf, zero16());
      #pragma unroll
      for (int r = 0; r < 16; ++r) {
        const int row = (r&3) + 8*(r>>2) + ho4;
        Xs[r] = X[r]*rk + (row == j ? 1.f : 0.f);
      }
      st_T(S11, j, ho4, Xs);
      mkfrag_row(S12, j, hoff, Bf);
      X = mmacc(aA, Bf, zero16());
      float rv[16];
      ld16_T(S22, j, ho4, rv);
      #pragma unroll
      for (int r = 0; r < 16; ++r) Xs[r] = (X[r] + qv[r]*rv[r]) * rk;
      st_T(S12, j, ho4, Xs);
      mkfrag_row(S22, j, hoff, Bf);
      X = mmacc(aT, Bf, zero16());
      #pragma unroll
      for (int r = 0; r < 16; ++r) {
        const int row = (r&3) + 8*(r>>2) + ho4;
        Xs[r] = (row == j ? 1.f : 0.f) - X[r]*rk;
      }
      st_T(S22, j, ho4, Xs);
    }
    __syncthreads();

    // ---------- squaring 0 ----------
    {
      Frag Ac, Br;
      float Xs[16];
      mkfrag_col(S11, j, hoff, Ac);
      mkfrag_row(S11, j, hoff, Br);
      f32x16 X1 = mmacc(Ac, Br, zero16());
      #pragma unroll
      for (int r = 0; r < 16; ++r) Xs[r] = X1[r];
      st_T(S11, j, ho4, Xs);
      Frag B12; mkfrag_row(S12, j, hoff, B12);
      f32x16 X2 = mmacc(Ac, B12, zero16());
      Frag A12; mkfrag_col(S12, j, hoff, A12);
      Frag B22; mkfrag_row(S22, j, hoff, B22);
      X2 = mmacc(A12, B22, X2);
      #pragma unroll
      for (int r = 0; r < 16; ++r) Xs[r] = X2[r];
      st_T(S12, j, ho4, Xs);
      Frag A22; mkfrag_col(S22, j, hoff, A22);
      f32x16 X3 = mmacc(A22, B22, zero16());
      #pragma unroll
      for (int r = 0; r < 16; ++r) Xs[r] = X3[r];
      st_T(S22, j, ho4, Xs);
    }
    __syncthreads();
    // ---------- squaring 1: R11, R12 only ----------
    {
      Frag Ac, Br;
      float Xs[16];
      mkfrag_col(S11, j, hoff, Ac);
      mkfrag_row(S11, j, hoff, Br);
      f32x16 X1 = mmacc(Ac, Br, zero16());
      Frag B12; mkfrag_row(S12, j, hoff, B12);
      f32x16 X2 = mmacc(Ac, B12, zero16());
      Frag A12; mkfrag_col(S12, j, hoff, A12);
      Frag B22; mkfrag_row(S22, j, hoff, B22);
      X2 = mmacc(A12, B22, X2);
      #pragma unroll
      for (int r = 0; r < 16; ++r) Xs[r] = X1[r];
      st_T(S11, j, ho4, Xs);
      #pragma unroll
      for (int r = 0; r < 16; ++r) Xs[r] = X2[r];
      st_T(S12, j, ho4, Xs);
    }
    __syncthreads();

    // ---------- Qd = 0.5*(Phi@E12 + (Phi@E12)^T) -> S22 ----------
    Frag PhiF;
    mkfrag_col(S11, j, hoff, PhiF);   // Phi[j][16c+8h+e] — A-frag AND B-frag
    {
      Frag B12; mkfrag_row(S12, j, hoff, B12);
      f32x16 Xq = mmacc(PhiF, B12, zero16());
      float Xs[16];
      #pragma unroll
      for (int r = 0; r < 16; ++r) Xs[r] = Xq[r];
      st_T(S22, j, ho4, Xs);
      __syncthreads();
      float sym[16];
      #pragma unroll
      for (int r = 0; r < 16; ++r) {
        const int row = (r&3) + 8*(r>>2) + ho4;
        const float tv = S22[row*32 + (j ^ XRS(row))];
        sym[r] = 0.5f * (Xs[r] + tv);
      }
      __syncthreads();
      st_T(S22, j, ho4, sym);
    }
    __syncthreads();

    // ---------- propagation: fully register-resident, barrier-free ----------
    float qdr[16];
    ld16_T(S22, j, ho4, qdr);          // qdr[r] = Qd[row(r)][j]
    for (int tt = 0; tt < 8; ++tt) {
      Frag covA;
      frag_from_cd(covreg, hh, covA);  // A-frag of cov (symmetric)
      f32x16 T1 = mmacc(covA, PhiF, zero16());       // T1 = cov @ Phi^T
      float T1a[16];
      #pragma unroll
      for (int r = 0; r < 16; ++r) T1a[r] = T1[r];
      Frag T1B;
      frag_from_cd(T1a, hh, T1B);      // B-frag of T1^T
      f32x16 C = mmacc(PhiF, T1B, zero16());         // cov' = Phi @ T1
      float Cs[16];
      #pragma unroll
      for (int r = 0; r < 16; ++r) Cs[r] = C[r] + qdr[r];
      // z' = Phi @ z from PhiF registers + shfl broadcast of z
      float zp = 0.f;
      #pragma unroll
      for (int e = 0; e < 8; ++e) {
        zp += (bf2f(PhiF.h0[e]) + bf2f(PhiF.l0[e])) * __shfl(zj, hoff + e);
        zp += (bf2f(PhiF.h1[e]) + bf2f(PhiF.l1[e])) * __shfl(zj, 16 + hoff + e);
      }
      zp += __shfl_xor(zp, 32);
      zj = zp;
      #pragma unroll
      for (int r = 0; r < 16; ++r) covreg[r] = Cs[r];
      float* cb = covout + (size_t)(s*8 + tt)*1024;
      #pragma unroll
      for (int r = 0; r < 16; ++r)
        cb[((r&3) + 8*(r>>2) + ho4)*32 + j] = Cs[r];
      if (t < 32) stout[(s*8 + tt)*32 + t] = zp;
    }
    __syncthreads();   // protect S12/S22 reuse by next segment's init
  }
}

// ---------------- launch ----------------
extern "C" void kernel_launch(void* const* d_in, const int* in_sizes, int n_in,
                              void* d_out, int out_size, void* d_ws, size_t ws_size,
                              hipStream_t stream) {
  const float* ctx  = (const float*)d_in[0];
  const float* z0   = (const float*)d_in[1];
  const float* S_W  = (const float*)d_in[2];
  const float* S_b  = (const float*)d_in[3];
  const float* L_W  = (const float*)d_in[4];
  const float* L_b  = (const float*)d_in[5];
  const float* G_W  = (const float*)d_in[6];
  const float* G_b  = (const float*)d_in[7];
  const float* Sg_W = (const float*)d_in[8];
  const float* Sg_b = (const float*)d_in[9];
  float* out = (float*)d_out;
  float* ws  = (float*)d_ws;

  // ws layout (f32 offsets):
  //   w_ 0 | q2 98304 | as_ 1015808 (12.6M f32) -> 13598720
  //   phase1 panels (ushort) @13598720: Ah/Al 8.9Mu, Bh3/Bl3 6.7Mu -> f32 21397504
  //   lt (f32, 8.4M) ALIASES phase1 panels @13598720 -> ends 21987328
  //   cx/lwT panels (ushort) @21987328: 2.62Mu -> ends f32 23298048 (93.2 MB)
  float* w_   = ws;
  float* q2   = ws + 98304;
  float* as_  = ws + 1015808;
  ushort_t* panAh  = (ushort_t*)(ws + 13598720);
  ushort_t* panAl  = panAh + 4456448;
  ushort_t* panBh3 = panAl + 4456448;
  ushort_t* panBl3 = panBh3 + 3342336;
  float* lt = ws + 13598720;
  ushort_t* cxh = (ushort_t*)(ws + 21987328);
  ushort_t* cxl = cxh + 524288;
  ushort_t* lwh = cxl + 524288;
  ushort_t* lwl = lwh + 786432;

  kA   <<<dim3(4096, 3), 64,  0, stream>>>(ctx, G_W, G_b, Sg_W, Sg_b, w_, q2);
  kCvtX<<<dim3(2048),    256, 0, stream>>>(ctx, cxh, cxl);
  kCvtL<<<dim3(64, 4, 3),256, 0, stream>>>(L_W, lwh, lwl);
  kCvtB<<<dim3(1024, 3), 256, 0, stream>>>(S_W, S_b, panBh3, panBl3);
  for (int s = 0; s < 3; ++s) {
    kCvtA<<<dim3(4096), 256, 0, stream>>>(ctx, w_, panAh, panAl, s);
    kB3  <<<dim3(8, 32), 256, 0, stream>>>(panAh, panAl,
                                           panBh3 + (size_t)s*1114112,
                                           panBl3 + (size_t)s*1114112,
                                           as_ + (size_t)s*4194304);
  }
  for (int s = 0; s < 3; ++s) {
    kL3 <<<dim3(16, 32), 256, 0, stream>>>(cxh, cxl, lwh, lwl, L_b, w_, lt, s);
    kLLT<<<dim3(1024),   128, 0, stream>>>(lt, as_, s);
  }
  kC11<<<dim3(4096),    64, 0, stream>>>(as_, q2, z0, out);
}

// Round 13
// 626.018 us; speedup vs baseline: 1.1062x; 1.1062x over previous
//
#include <hip/hip_runtime.h>
#include <math.h>

// TVKoopmanMoE: B=4096, C=128, D=32, K=8, R=8, NSEG=3, STEPS=8 each, DT=0.1
//  - kA: gates w (softmax) + diag^2
//  - kT: transpose all (s,c,k) 32x32 S_W matrices -> SWT (aliased over as_)
//  - kCvtB: V2^T hi/lo bf16 panels, fully coalesced via SW rows + SWT rows
//  - AS GEMM via MFMA bf16 hi/lo split (kCvtA/kB3), bias folded via K-ext
//  - kL3: Ltil GEMM via MFMA hi/lo; kLLT: AS -= Ltil Ltil^T
//  - kC12: ONE WAVE per b expm+propagation (R11's proven kC10 structure),
//    Taylor ORDER=4 (remainder ~1e-6 << 1e-4 split error).

#define NSEGC 3
#define BSZ   4096
#define MUC   0.14861455999447191f   /* -ln(0.7)/(0.1*24) */
#define XSC   0.025f                 /* DT / 2^SQ = 0.1/4 */
#define XRS(r) (((r) & 7) << 2)

typedef unsigned short ushort_t;
typedef unsigned int uint_t;
typedef __attribute__((ext_vector_type(8))) short bf16x8;
typedef __attribute__((ext_vector_type(16))) float f32x16;

__device__ __forceinline__ void ld4(float d[4], const float* p) {
  const float4 v = *(const float4*)p; d[0]=v.x; d[1]=v.y; d[2]=v.z; d[3]=v.w;
}
__device__ __forceinline__ void st4(float* p, const float d[4]) {
  *(float4*)p = make_float4(d[0], d[1], d[2], d[3]);
}
__device__ __forceinline__ unsigned short bf_rne(float x) {
  unsigned b = __float_as_uint(x);
  unsigned r = b + 0x7FFFu + ((b >> 16) & 1u);
  return (unsigned short)(r >> 16);
}
__device__ __forceinline__ float bf2f(short v) {
  return __uint_as_float(((uint_t)(unsigned short)v) << 16);
}

// ---------------- kA: gates (softmax(logits/2)) and diag^2 ----------------
__global__ __launch_bounds__(64) void kA(const float* __restrict__ ctx,
    const float* __restrict__ GW, const float* __restrict__ Gb,
    const float* __restrict__ SgW, const float* __restrict__ Sgb,
    float* __restrict__ Wsm, float* __restrict__ Q2) {
  const int b = blockIdx.x, s = blockIdx.y, l = threadIdx.x;
  __shared__ float c[128];
  c[l]      = ctx[(size_t)b*128 + l];
  c[l + 64] = ctx[(size_t)b*128 + 64 + l];
  __syncthreads();
  if (l < 8) {
    float acc = Gb[s*8 + l];
    #pragma unroll 4
    for (int q = 0; q < 128; ++q) acc += c[q] * GW[(size_t)(s*128 + q)*8 + l];
    float li = acc * 0.5f;            // / TEMP (=2)
    float m = li;
    m = fmaxf(m, __shfl_xor(m, 1));
    m = fmaxf(m, __shfl_xor(m, 2));
    m = fmaxf(m, __shfl_xor(m, 4));
    float e = expf(li - m);
    float sum = e;
    sum += __shfl_xor(sum, 1);
    sum += __shfl_xor(sum, 2);
    sum += __shfl_xor(sum, 4);
    Wsm[((size_t)s*BSZ + b)*8 + l] = e / sum;
  } else if (l < 40) {
    const int d = l - 8;
    float acc = Sgb[s*32 + d];
    #pragma unroll 4
    for (int q = 0; q < 128; ++q) acc += c[q] * SgW[(size_t)(s*128 + q)*32 + d];
    float sp = fmaxf(acc, 0.f) + log1pf(expf(-fabsf(acc)));  // stable softplus
    float dg = fminf(sp, 1.0f);
    Q2[((size_t)s*BSZ + b)*32 + d] = dg * dg;
  }
}

// -------- kT: SWT[(s*1024+kc)*1024 + n] = M_{s,c,k}[(n&31)*32 + (n>>5)] ------
__global__ __launch_bounds__(256) void kT(const float* __restrict__ SW,
                                          float* __restrict__ SWT) {
  __shared__ float mt[1056];   // 32 rows x 33
  const int kc = blockIdx.x, s = blockIdx.y, t = threadIdx.x;
  const int k = kc >> 7, c = kc & 127;
  const float* src = SW + ((size_t)(s*128 + c))*8192 + (size_t)k*1024;
  float* dst = SWT + ((size_t)s*1024 + kc)*1024;
  for (int i = t; i < 1024; i += 256) mt[(i >> 5)*33 + (i & 31)] = src[i];
  __syncthreads();
  for (int i = t; i < 1024; i += 256) dst[i] = mt[(i & 31)*33 + (i >> 5)];
}

// -------- kCvtB: B'[s][n][kc] hi/lo bf16, coalesced (16-n groups) -----------
// v(n,kc<1024) = SW[c][k][n] - M[nT] (= SWT[kc][n]); kc in [1024,1032): Sb skew.
__global__ __launch_bounds__(256) void kCvtB(const float* __restrict__ SW,
    const float* __restrict__ SWT, const float* __restrict__ Sb,
    ushort_t* __restrict__ Bh, ushort_t* __restrict__ Bl) {
  const int s = blockIdx.y, t = threadIdx.x;
  const int n0 = blockIdx.x * 16;
  const int tn = t & 15, tck = t >> 4;
  const int n = n0 + tn;
  const int nT = (n & 31)*32 + (n >> 5);
  ushort_t* bh = Bh + (size_t)s*1114112;
  ushort_t* bl = Bl + (size_t)s*1114112;
  for (int kc0 = 0; kc0 < 1088; kc0 += 16) {
    const int kc = kc0 + tck;
    float v = 0.f;
    if (kc < 1024) {
      const int k = kc >> 7, c = kc & 127;
      v = SW[((size_t)(s*128 + c))*8192 + (size_t)k*1024 + n]
        - SWT[((size_t)s*1024 + kc)*1024 + n];
    } else if (kc < 1032) {
      const int k2 = kc - 1024;
      const float* base = Sb + (size_t)s*8192 + (size_t)k2*1024;
      v = base[n] - base[nT];
    }
    const unsigned short h = bf_rne(v);
    bh[(size_t)n*1088 + kc] = h;
    bl[(size_t)n*1088 + kc] = bf_rne(v - __uint_as_float(((unsigned)h) << 16));
  }
}

// -------- kCvtX: ctx -> hi/lo bf16 panels [4096][128] ----------------------
__global__ __launch_bounds__(256) void kCvtX(const float* __restrict__ ctx,
    ushort_t* __restrict__ Xh, ushort_t* __restrict__ Xl) {
  const int idx = blockIdx.x*256 + threadIdx.x;
  const float v = ctx[idx];
  const unsigned short h = bf_rne(v);
  Xh[idx] = h;
  Xl[idx] = bf_rne(v - __uint_as_float(((unsigned)h) << 16));
}

// -------- kCvtL: lwT[s][n][c] = L_W[s][c][n] hi/lo bf16 --------------------
__global__ __launch_bounds__(256) void kCvtL(const float* __restrict__ LW,
    ushort_t* __restrict__ Lh, ushort_t* __restrict__ Ll) {
  __shared__ float tile[32][33];
  const int nb = blockIdx.x * 32, cb = blockIdx.y * 32, s = blockIdx.z;
  const int tx = threadIdx.x & 31, ty = threadIdx.x >> 5;
  for (int r = ty; r < 32; r += 8)
    tile[r][tx] = LW[((size_t)(s*128 + cb + r))*2048 + nb + tx];
  __syncthreads();
  for (int r = ty; r < 32; r += 8) {
    const float v = tile[tx][r];          // LW[cb+tx][nb+r]
    const unsigned short h = bf_rne(v);
    const size_t o = ((size_t)s*2048 + nb + r)*128 + cb + tx;
    Lh[o] = h;
    Ll[o] = bf_rne(v - __uint_as_float(((unsigned)h) << 16));
  }
}

// -------- kCvtA: A'[b][kc] hi/lo bf16; kc<1024: w[k]*ctx[c]; 1024..1031: w ---
__global__ __launch_bounds__(256) void kCvtA(const float* __restrict__ ctx,
    const float* __restrict__ Wsm, ushort_t* __restrict__ Ah,
    ushort_t* __restrict__ Al, int s) {
  __shared__ float cs[128];
  __shared__ float wwv[8];
  const int b = blockIdx.x, t = threadIdx.x;
  if (t < 128) cs[t] = ctx[(size_t)b*128 + t];
  else if (t < 136) wwv[t - 128] = Wsm[((size_t)s*BSZ + b)*8 + (t - 128)];
  __syncthreads();
  for (int kc = t; kc < 1088; kc += 256) {
    float v = 0.f;
    if (kc < 1024) v = wwv[kc >> 7] * cs[kc & 127];
    else if (kc < 1032) v = wwv[kc - 1024];
    const unsigned short h = bf_rne(v);
    const float hf = __uint_as_float(((unsigned)h) << 16);
    Ah[(size_t)b*1088 + kc] = h;
    Al[(size_t)b*1088 + kc] = bf_rne(v - hf);
  }
}

// -------- kB3: AS_seg = A' @ B'^T via 32x32x16 bf16 MFMA, 3-product hi/lo ----
__global__ __launch_bounds__(256) void kB3(const ushort_t* __restrict__ Ah,
    const ushort_t* __restrict__ Al, const ushort_t* __restrict__ Bh,
    const ushort_t* __restrict__ Bl, float* __restrict__ ASseg) {
  __shared__ ushort_t sArr[2][2][8192];   // [buf][A/B][128 rows x 64 cols]
  const int t = threadIdx.x;
  const int l = t & 63, w = t >> 6;
  const int hh = l >> 5, lane31 = l & 31;
  const int nb = blockIdx.x * 128, bb = blockIdx.y * 128;
  const int wr0 = (w & 1) * 64, wc0 = (w >> 1) * 64;

  const ushort_t* APT[3] = {Ah, Ah, Al};
  const ushort_t* BPT[3] = {Bh, Bl, Bh};

  f32x16 acc[2][2];
  #pragma unroll
  for (int a = 0; a < 2; ++a)
    #pragma unroll
    for (int bq = 0; bq < 2; ++bq)
      #pragma unroll
      for (int e = 0; e < 16; ++e) acc[a][bq][e] = 0.f;

  #define STAGE(buf, it) do {                                                  \
    const int p_ = (it) / 17, ks_ = (it) - p_*17;                              \
    const ushort_t* As_ = APT[p_];                                             \
    const ushort_t* Bs_ = BPT[p_];                                             \
    _Pragma("unroll")                                                          \
    for (int i_ = 0; i_ < 4; ++i_) {                                           \
      const int gidx_ = i_*256 + t;                                            \
      const int r_ = gidx_ >> 3, g_ = gidx_ & 7;                               \
      const int gs_ = g_ ^ (r_ & 7);                                           \
      const ushort_t* srcA_ = As_ + (size_t)(bb + r_)*1088 + ks_*64 + gs_*8;   \
      const ushort_t* srcB_ = Bs_ + (size_t)(nb + r_)*1088 + ks_*64 + gs_*8;   \
      __builtin_amdgcn_global_load_lds(                                        \
        (const __attribute__((address_space(1))) unsigned int*)srcA_,          \
        (__attribute__((address_space(3))) unsigned int*)&sArr[buf][0][(i_*256 + w*64)*8], \
        16, 0, 0);                                                             \
      __builtin_amdgcn_global_load_lds(                                        \
        (const __attribute__((address_space(1))) unsigned int*)srcB_,          \
        (__attribute__((address_space(3))) unsigned int*)&sArr[buf][1][(i_*256 + w*64)*8], \
        16, 0, 0);                                                             \
    }                                                                          \
  } while (0)

  STAGE(0, 0);
  int cur = 0;
  #pragma unroll 1
  for (int it = 0; it < 51; ++it) {
    __syncthreads();                      // drain loads into buf[cur]
    if (it + 1 < 51) STAGE(cur ^ 1, it + 1);
    const ushort_t* lA = &sArr[cur][0][0];
    const ushort_t* lB = &sArr[cur][1][0];
    #pragma unroll
    for (int kc = 0; kc < 4; ++kc) {
      bf16x8 af[2], bfr[2];
      #pragma unroll
      for (int rt = 0; rt < 2; ++rt) {
        const int row = wr0 + rt*32 + lane31;
        const int slot = (kc*2 + hh) ^ (row & 7);
        af[rt] = *(const bf16x8*)&lA[row*64 + slot*8];
      }
      #pragma unroll
      for (int ct = 0; ct < 2; ++ct) {
        const int row = wc0 + ct*32 + lane31;
        const int slot = (kc*2 + hh) ^ (row & 7);
        bfr[ct] = *(const bf16x8*)&lB[row*64 + slot*8];
      }
      #pragma unroll
      for (int rt = 0; rt < 2; ++rt)
        #pragma unroll
        for (int ct = 0; ct < 2; ++ct)
          acc[rt][ct] = __builtin_amdgcn_mfma_f32_32x32x16_bf16(
              af[rt], bfr[ct], acc[rt][ct], 0, 0, 0);
    }
    cur ^= 1;
  }
  #undef STAGE

  #pragma unroll
  for (int rt = 0; rt < 2; ++rt)
    #pragma unroll
    for (int ct = 0; ct < 2; ++ct) {
      float* o = ASseg + ((size_t)(bb + wr0 + rt*32))*1024 + nb + wc0 + ct*32 + lane31;
      #pragma unroll
      for (int reg = 0; reg < 16; ++reg) {
        const int row = (reg & 3) + 8*(reg >> 2) + 4*hh;
        o[(size_t)row*1024] = acc[rt][ct][reg];
      }
    }
}

// -------- kL3: lt = (ctx @ L_W + Lb)*sqrt(w) via MFMA hi/lo (K=128) --------
__global__ __launch_bounds__(256) void kL3(const ushort_t* __restrict__ Xh,
    const ushort_t* __restrict__ Xl, const ushort_t* __restrict__ Lh,
    const ushort_t* __restrict__ Ll, const float* __restrict__ Lb,
    const float* __restrict__ Wsm, float* __restrict__ lt, int s) {
  __shared__ ushort_t sArr[2][2][8192];
  __shared__ float sqw[128][8];
  const int t = threadIdx.x;
  const int l = t & 63, w = t >> 6;
  const int hh = l >> 5, lane31 = l & 31;
  const int nb = blockIdx.x * 128, bb = blockIdx.y * 128;
  const int wr0 = (w & 1) * 64, wc0 = (w >> 1) * 64;
  for (int i = t; i < 1024; i += 256)
    sqw[i >> 3][i & 7] = sqrtf(Wsm[((size_t)s*BSZ + bb + (i >> 3))*8 + (i & 7)]);

  const ushort_t* APT[3] = {Xh, Xh, Xl};
  const ushort_t* BPT[3] = {Lh + (size_t)s*262144, Ll + (size_t)s*262144,
                            Lh + (size_t)s*262144};

  f32x16 acc[2][2];
  #pragma unroll
  for (int a = 0; a < 2; ++a)
    #pragma unroll
    for (int bq = 0; bq < 2; ++bq)
      #pragma unroll
      for (int e = 0; e < 16; ++e) acc[a][bq][e] = 0.f;

  #define STAGEL(buf, it) do {                                                 \
    const int p_ = (it) >> 1, ks_ = (it) & 1;                                  \
    const ushort_t* As_ = APT[p_];                                             \
    const ushort_t* Bs_ = BPT[p_];                                             \
    _Pragma("unroll")                                                          \
    for (int i_ = 0; i_ < 4; ++i_) {                                           \
      const int gidx_ = i_*256 + t;                                            \
      const int r_ = gidx_ >> 3, g_ = gidx_ & 7;                               \
      const int gs_ = g_ ^ (r_ & 7);                                           \
      const ushort_t* srcA_ = As_ + (size_t)(bb + r_)*128 + ks_*64 + gs_*8;    \
      const ushort_t* srcB_ = Bs_ + (size_t)(nb + r_)*128 + ks_*64 + gs_*8;    \
      __builtin_amdgcn_global_load_lds(                                        \
        (const __attribute__((address_space(1))) unsigned int*)srcA_,          \
        (__attribute__((address_space(3))) unsigned int*)&sArr[buf][0][(i_*256 + w*64)*8], \
        16, 0, 0);                                                             \
      __builtin_amdgcn_global_load_lds(                                        \
        (const __attribute__((address_space(1))) unsigned int*)srcB_,          \
        (__attribute__((address_space(3))) unsigned int*)&sArr[buf][1][(i_*256 + w*64)*8], \
        16, 0, 0);                                                             \
    }                                                                          \
  } while (0)

  STAGEL(0, 0);
  int cur = 0;
  #pragma unroll 1
  for (int it = 0; it < 6; ++it) {
    __syncthreads();
    if (it + 1 < 6) STAGEL(cur ^ 1, it + 1);
    const ushort_t* lA = &sArr[cur][0][0];
    const ushort_t* lB = &sArr[cur][1][0];
    #pragma unroll
    for (int kc = 0; kc < 4; ++kc) {
      bf16x8 af[2], bfr[2];
      #pragma unroll
      for (int rt = 0; rt < 2; ++rt) {
        const int row = wr0 + rt*32 + lane31;
        const int slot = (kc*2 + hh) ^ (row & 7);
        af[rt] = *(const bf16x8*)&lA[row*64 + slot*8];
      }
      #pragma unroll
      for (int ct = 0; ct < 2; ++ct) {
        const int row = wc0 + ct*32 + lane31;
        const int slot = (kc*2 + hh) ^ (row & 7);
        bfr[ct] = *(const bf16x8*)&lB[row*64 + slot*8];
      }
      #pragma unroll
      for (int rt = 0; rt < 2; ++rt)
        #pragma unroll
        for (int ct = 0; ct < 2; ++ct)
          acc[rt][ct] = __builtin_amdgcn_mfma_f32_32x32x16_bf16(
              af[rt], bfr[ct], acc[rt][ct], 0, 0, 0);
    }
    cur ^= 1;
  }
  #undef STAGEL

  // epilogue: (acc + Lb[n]) * sqrt(w[b][n>>8]) -> lt[b][ltcol(n)]
  #pragma unroll
  for (int rt = 0; rt < 2; ++rt)
    #pragma unroll
    for (int ct = 0; ct < 2; ++ct) {
      const int n = nb + wc0 + ct*32 + lane31;
      const float lb = Lb[(size_t)s*2048 + n];
      const int kidx = n >> 8;
      const int ltcol = (kidx << 8) + ((n & 7) << 5) + ((n >> 3) & 31);
      #pragma unroll
      for (int reg = 0; reg < 16; ++reg) {
        const int lrow = wr0 + rt*32 + (reg & 3) + 8*(reg >> 2) + 4*hh;
        lt[(size_t)(bb + lrow)*2048 + ltcol] =
            (acc[rt][ct][reg] + lb) * sqw[lrow][kidx];
      }
    }
}

// ---------------- kLLT: AS -= Ltil Ltil^T  (4 b per block) ----------------
__global__ __launch_bounds__(128) void kLLT(const float* __restrict__ LT,
                                            float* __restrict__ AS, int s) {
  __shared__ float L4[4][64][32];
  const int t = threadIdx.x;
  const int bbase = blockIdx.x * 4;
  {
    float* l4f = &L4[0][0][0];
    const float* src = LT + (size_t)bbase * 2048;
    for (int i = t*4; i < 8192; i += 512)
      *(float4*)&l4f[i] = *(const float4*)&src[i];
  }
  __syncthreads();
  const int b = t >> 5, u = t & 31;
  const int i0 = (u >> 2) * 4, j0 = (u & 3) * 8;
  float acc[4][8] = {};
  #pragma unroll 8
  for (int kr = 0; kr < 64; ++kr) {
    float pa[4], pb[8];
    ld4(pa, &L4[b][kr][i0]);
    ld4(pb, &L4[b][kr][j0]); ld4(pb + 4, &L4[b][kr][j0 + 4]);
    #pragma unroll
    for (int ii = 0; ii < 4; ++ii)
      #pragma unroll
      for (int jj = 0; jj < 8; ++jj) acc[ii][jj] += pa[ii] * pb[jj];
  }
  float* dst = AS + ((size_t)s*BSZ + bbase + b)*1024;
  for (int ii = 0; ii < 4; ++ii) {
    float x[8];
    ld4(x, &dst[(i0+ii)*32 + j0]); ld4(x + 4, &dst[(i0+ii)*32 + j0 + 4]);
    #pragma unroll
    for (int jj = 0; jj < 8; ++jj) x[jj] -= acc[ii][jj];
    st4(&dst[(i0+ii)*32 + j0], x); st4(&dst[(i0+ii)*32 + j0 + 4], &x[4]);
  }
}

// ================= kC12: MFMA hi/lo expm + propagation, one wave per b ========
// R11's proven kC10 structure; Taylor ORDER=4.
struct Frag { bf16x8 h0, l0, h1, l1; };

__device__ __forceinline__ void cvt8(const float x[8], bf16x8& hi, bf16x8& lo) {
  uint_t h[4], l[4];
  #pragma unroll
  for (int p = 0; p < 4; ++p) {
    const uint_t b0 = __float_as_uint(x[2*p]);
    const uint_t b1 = __float_as_uint(x[2*p + 1]);
    h[p] = __builtin_amdgcn_perm(b1, b0, 0x07060302u);
    const float l0f = x[2*p]     - __uint_as_float(b0 & 0xFFFF0000u);  // exact
    const float l1f = x[2*p + 1] - __uint_as_float(b1 & 0xFFFF0000u);  // exact
    l[p] = __builtin_amdgcn_perm(__float_as_uint(l1f), __float_as_uint(l0f),
                                 0x07060302u);
  }
  hi = __builtin_bit_cast(bf16x8, make_uint4(h[0], h[1], h[2], h[3]));
  lo = __builtin_bit_cast(bf16x8, make_uint4(l[0], l[1], l[2], l[3]));
}
__device__ __forceinline__ void rd_row8(const float* M, int r, int kb, float o[8]) {
  const float* p = M + r*32;
  ld4(o,     p + ((kb)     ^ XRS(r)));
  ld4(o + 4, p + ((kb + 4) ^ XRS(r)));
}
__device__ __forceinline__ void rd_col8(const float* M, int c, int kb, float o[8]) {
  #pragma unroll
  for (int e = 0; e < 8; ++e) o[e] = M[(kb + e)*32 + (c ^ XRS(kb + e))];
}
__device__ __forceinline__ void mkfrag_row(const float* M, int r, int hoff, Frag& f) {
  float t0[8], t1[8];
  rd_row8(M, r, hoff, t0);
  rd_row8(M, r, 16 + hoff, t1);
  cvt8(t0, f.h0, f.l0);
  cvt8(t1, f.h1, f.l1);
}
__device__ __forceinline__ void mkfrag_col(const float* M, int c, int hoff, Frag& f) {
  float t0[8], t1[8];
  rd_col8(M, c, hoff, t0);
  rd_col8(M, c, 16 + hoff, t1);
  cvt8(t0, f.h0, f.l0);
  cvt8(t1, f.h1, f.l1);
}
__device__ __forceinline__ f32x16 mmacc(const Frag& A, const Frag& B, f32x16 acc) {
  acc = __builtin_amdgcn_mfma_f32_32x32x16_bf16(A.h0, B.h0, acc, 0, 0, 0);
  acc = __builtin_amdgcn_mfma_f32_32x32x16_bf16(A.h0, B.l0, acc, 0, 0, 0);
  acc = __builtin_amdgcn_mfma_f32_32x32x16_bf16(A.l0, B.h0, acc, 0, 0, 0);
  acc = __builtin_amdgcn_mfma_f32_32x32x16_bf16(A.h1, B.h1, acc, 0, 0, 0);
  acc = __builtin_amdgcn_mfma_f32_32x32x16_bf16(A.h1, B.l1, acc, 0, 0, 0);
  acc = __builtin_amdgcn_mfma_f32_32x32x16_bf16(A.l1, B.h1, acc, 0, 0, 0);
  return acc;
}
__device__ __forceinline__ f32x16 zero16() {
  f32x16 z = {0.f,0.f,0.f,0.f,0.f,0.f,0.f,0.f,0.f,0.f,0.f,0.f,0.f,0.f,0.f,0.f};
  return z;
}
__device__ __forceinline__ void st_T(float* M, int j, int ho4, const float v[16]) {
  float* p = M + j*32;
  #pragma unroll
  for (int m = 0; m < 4; ++m) st4(p + ((8*m + ho4) ^ XRS(j)), v + 4*m);
}
__device__ __forceinline__ void ld16_T(const float* M, int j, int ho4, float o[16]) {
  const float* p = M + j*32;
  #pragma unroll
  for (int m = 0; m < 4; ++m) ld4(o + 4*m, p + ((8*m + ho4) ^ XRS(j)));
}

__global__ __launch_bounds__(64, 3) void kC12(const float* __restrict__ AS,
    const float* __restrict__ Q2, const float* __restrict__ z0,
    float* __restrict__ out) {
  __shared__ float S11[1024];  // R11^T (Phi^T) ; G scratch in propagation
  __shared__ float S12[1024];  // a staging; R12^T (E12^T); cov buffer
  __shared__ float S22[1024];  // R22^T ; later Qd
  __shared__ float zarr[32], qds[32];
  const int b = blockIdx.x, t = threadIdx.x;
  const int j = t & 31, hh = t >> 5;
  const int hoff = hh * 8, ho4 = hh * 4;

  if (t < 32) zarr[t] = z0[(size_t)b*32 + t];
  float covreg[16];
  #pragma unroll
  for (int r = 0; r < 16; ++r) covreg[r] = 0.f;
  __syncthreads();

  float* covout = out + 3145728 + (size_t)b*24576;
  float* stout  = out + (size_t)b*768;

  for (int s = 0; s < NSEGC; ++s) {
    // ---------- init: load A, -muI, frob clamp, scale; stage a via S12 -------
    if (t < 32) qds[t] = Q2[((size_t)s*BSZ + b)*32 + t] * XSC;
    const float* asb = AS + ((size_t)s*BSZ + b)*1024;
    float av[16];
    #pragma unroll
    for (int m = 0; m < 4; ++m) ld4(av + 4*m, &asb[j*32 + 16*hh + 4*m]);
    #pragma unroll
    for (int i = 0; i < 16; ++i) if (16*hh + i == j) av[i] -= MUC;
    float ssq = 0.f;
    #pragma unroll
    for (int i = 0; i < 16; ++i) ssq += av[i]*av[i];
    #pragma unroll
    for (int off = 1; off < 64; off <<= 1) ssq += __shfl_xor(ssq, off);
    const float frob = sqrtf(ssq);
    const float sc = (frob > 3.0f ? 3.0f / (frob + 1e-6f) : 1.0f) * XSC;
    #pragma unroll
    for (int i = 0; i < 16; ++i) av[i] *= sc;
    __syncthreads();
    #pragma unroll
    for (int m = 0; m < 4; ++m)
      st4(&S12[j*32 + ((16*hh + 4*m) ^ XRS(j))], av + 4*m);  // S12 = a (rows)
    __syncthreads();
    Frag aA, aT;
    mkfrag_row(S12, j, hoff, aA);   // A-frag of a
    mkfrag_col(S12, j, hoff, aT);   // A-frag of a^T
    __syncthreads();
    #pragma unroll
    for (int m = 0; m < 4; ++m) {
      float id[4], zo[4] = {0.f, 0.f, 0.f, 0.f};
      #pragma unroll
      for (int e = 0; e < 4; ++e) id[e] = (16*hh + 4*m + e == j) ? 1.f : 0.f;
      st4(&S11[j*32 + ((16*hh + 4*m) ^ XRS(j))], id);
      st4(&S22[j*32 + ((16*hh + 4*m) ^ XRS(j))], id);
      st4(&S12[j*32 + ((16*hh + 4*m) ^ XRS(j))], zo);
    }
    __syncthreads();
    float qv[16];
    #pragma unroll
    for (int r = 0; r < 16; ++r) qv[r] = qds[(r&3) + 8*(r>>2) + ho4];

    // ---------- Taylor Horner ORDER=4 on X=[[a,q],[0,-a^T]] (transposed blocks)
    for (int k = 4; k >= 1; --k) {
      const float rk = 1.0f / (float)k;
      Frag Bf;
      float Xs[16];
      mkfrag_row(S11, j, hoff, Bf);
      f32x16 X = mmacc(aA, Bf, zero16());
      #pragma unroll
      for (int r = 0; r < 16; ++r) {
        const int row = (r&3) + 8*(r>>2) + ho4;
        Xs[r] = X[r]*rk + (row == j ? 1.f : 0.f);
      }
      st_T(S11, j, ho4, Xs);
      mkfrag_row(S12, j, hoff, Bf);
      X = mmacc(aA, Bf, zero16());
      float rv[16];
      ld16_T(S22, j, ho4, rv);
      #pragma unroll
      for (int r = 0; r < 16; ++r) Xs[r] = (X[r] + qv[r]*rv[r]) * rk;
      st_T(S12, j, ho4, Xs);
      mkfrag_row(S22, j, hoff, Bf);
      X = mmacc(aT, Bf, zero16());
      #pragma unroll
      for (int r = 0; r < 16; ++r) {
        const int row = (r&3) + 8*(r>>2) + ho4;
        Xs[r] = (row == j ? 1.f : 0.f) - X[r]*rk;
      }
      st_T(S22, j, ho4, Xs);
    }
    __syncthreads();

    // ---------- squaring 0 ----------
    {
      Frag Ac, Br;
      float Xs[16];
      mkfrag_col(S11, j, hoff, Ac);
      mkfrag_row(S11, j, hoff, Br);
      f32x16 X1 = mmacc(Ac, Br, zero16());
      #pragma unroll
      for (int r = 0; r < 16; ++r) Xs[r] = X1[r];
      st_T(S11, j, ho4, Xs);
      Frag B12; mkfrag_row(S12, j, hoff, B12);
      f32x16 X2 = mmacc(Ac, B12, zero16());
      Frag A12; mkfrag_col(S12, j, hoff, A12);
      Frag B22; mkfrag_row(S22, j, hoff, B22);
      X2 = mmacc(A12, B22, X2);
      #pragma unroll
      for (int r = 0; r < 16; ++r) Xs[r] = X2[r];
      st_T(S12, j, ho4, Xs);
      Frag A22; mkfrag_col(S22, j, hoff, A22);
      f32x16 X3 = mmacc(A22, B22, zero16());
      #pragma unroll
      for (int r = 0; r < 16; ++r) Xs[r] = X3[r];
      st_T(S22, j, ho4, Xs);
    }
    __syncthreads();
    // ---------- squaring 1: R11, R12 only ----------
    {
      Frag Ac, Br;
      float Xs[16];
      mkfrag_col(S11, j, hoff, Ac);
      mkfrag_row(S11, j, hoff, Br);
      f32x16 X1 = mmacc(Ac, Br, zero16());
      Frag B12; mkfrag_row(S12, j, hoff, B12);
      f32x16 X2 = mmacc(Ac, B12, zero16());
      Frag A12; mkfrag_col(S12, j, hoff, A12);
      Frag B22; mkfrag_row(S22, j, hoff, B22);
      X2 = mmacc(A12, B22, X2);
      #pragma unroll
      for (int r = 0; r < 16; ++r) Xs[r] = X1[r];
      st_T(S11, j, ho4, Xs);
      #pragma unroll
      for (int r = 0; r < 16; ++r) Xs[r] = X2[r];
      st_T(S12, j, ho4, Xs);
    }
    __syncthreads();

    // ---------- Qd = 0.5*(Phi@E12 + (Phi@E12)^T) -> S22 ----------
    Frag PhiF;
    mkfrag_col(S11, j, hoff, PhiF);   // lane j holds Phi[j][hoff+e], [16+hoff+e]
    {
      Frag B12; mkfrag_row(S12, j, hoff, B12);
      f32x16 Xq = mmacc(PhiF, B12, zero16());
      float Xs[16];
      #pragma unroll
      for (int r = 0; r < 16; ++r) Xs[r] = Xq[r];
      st_T(S22, j, ho4, Xs);
      __syncthreads();
      float sym[16];
      #pragma unroll
      for (int r = 0; r < 16; ++r) {
        const int row = (r&3) + 8*(r>>2) + ho4;
        const float tv = S22[row*32 + (j ^ XRS(row))];
        sym[r] = 0.5f * (Xs[r] + tv);
      }
      __syncthreads();
      st_T(S22, j, ho4, sym);
    }
    __syncthreads();

    // ---------- stage cov (covreg, C/D order) into S12 (E12 dead) ------------
    st_T(S12, j, ho4, covreg);
    __syncthreads();

    // ---------- 8 propagation steps: cov <- Phi cov Phi^T + Qd ; z <- Phi z ---
    for (int tt = 0; tt < 8; ++tt) {
      Frag Bcov; mkfrag_row(S12, j, hoff, Bcov);
      f32x16 G = mmacc(PhiF, Bcov, zero16());
      float Gs[16];
      #pragma unroll
      for (int r = 0; r < 16; ++r) Gs[r] = G[r];
      st_T(S11, j, ho4, Gs);                         // S11 = G^T (Phi in regs)
      Frag AG; mkfrag_col(S11, j, hoff, AG);
      f32x16 C = mmacc(AG, PhiF, zero16());
      float qdv[16], Cs[16];
      ld16_T(S22, j, ho4, qdv);
      #pragma unroll
      for (int r = 0; r < 16; ++r) Cs[r] = C[r] + qdv[r];
      // z' = Phi@z from PhiF registers (hi+lo reconstruction)
      float zp = 0.f;
      #pragma unroll
      for (int e = 0; e < 8; ++e) {
        zp += (bf2f(PhiF.h0[e]) + bf2f(PhiF.l0[e])) * zarr[hoff + e];
        zp += (bf2f(PhiF.h1[e]) + bf2f(PhiF.l1[e])) * zarr[16 + hoff + e];
      }
      zp += __shfl_xor(zp, 32);
      st_T(S12, j, ho4, Cs);
      #pragma unroll
      for (int r = 0; r < 16; ++r) covreg[r] = Cs[r];
      float* cb = covout + (size_t)(s*8 + tt)*1024;
      #pragma unroll
      for (int r = 0; r < 16; ++r)
        cb[((r&3) + 8*(r>>2) + ho4)*32 + j] = Cs[r];
      if (t < 32) {
        zarr[t] = zp;
        stout[(s*8 + tt)*32 + t] = zp;
      }
      __syncthreads();
    }
  }
}

// ---------------- launch ----------------
extern "C" void kernel_launch(void* const* d_in, const int* in_sizes, int n_in,
                              void* d_out, int out_size, void* d_ws, size_t ws_size,
                              hipStream_t stream) {
  const float* ctx  = (const float*)d_in[0];
  const float* z0   = (const float*)d_in[1];
  const float* S_W  = (const float*)d_in[2];
  const float* S_b  = (const float*)d_in[3];
  const float* L_W  = (const float*)d_in[4];
  const float* L_b  = (const float*)d_in[5];
  const float* G_W  = (const float*)d_in[6];
  const float* G_b  = (const float*)d_in[7];
  const float* Sg_W = (const float*)d_in[8];
  const float* Sg_b = (const float*)d_in[9];
  float* out = (float*)d_out;
  float* ws  = (float*)d_ws;

  // ws layout (f32 offsets):
  //   w_ 0 | q2 98304 | as_ 1015808 (12.6M f32) -> 13598720
  //   SWT (3.1M f32) ALIASES as_ start (dead before kB3 writes as_)
  //   phase1 panels (ushort) @13598720: Ah/Al 8.9Mu, Bh3/Bl3 6.7Mu -> f32 21397504
  //   lt (f32, 8.4M) ALIASES phase1 panels @13598720 -> ends 21987328
  //   cx/lwT panels (ushort) @21987328: 2.62Mu -> ends f32 23298048 (93.2 MB)
  float* w_   = ws;
  float* q2   = ws + 98304;
  float* as_  = ws + 1015808;
  float* swt  = ws + 1015808;          // aliases as_ head; dead before kB3
  ushort_t* panAh  = (ushort_t*)(ws + 13598720);
  ushort_t* panAl  = panAh + 4456448;
  ushort_t* panBh3 = panAl + 4456448;
  ushort_t* panBl3 = panBh3 + 3342336;
  float* lt = ws + 13598720;
  ushort_t* cxh = (ushort_t*)(ws + 21987328);
  ushort_t* cxl = cxh + 524288;
  ushort_t* lwh = cxl + 524288;
  ushort_t* lwl = lwh + 786432;

  kA   <<<dim3(4096, 3), 64,  0, stream>>>(ctx, G_W, G_b, Sg_W, Sg_b, w_, q2);
  kCvtX<<<dim3(2048),    256, 0, stream>>>(ctx, cxh, cxl);
  kCvtL<<<dim3(64, 4, 3),256, 0, stream>>>(L_W, lwh, lwl);
  kT   <<<dim3(1024, 3), 256, 0, stream>>>(S_W, swt);
  kCvtB<<<dim3(64, 3),   256, 0, stream>>>(S_W, swt, S_b, panBh3, panBl3);
  for (int s = 0; s < 3; ++s) {
    kCvtA<<<dim3(4096), 256, 0, stream>>>(ctx, w_, panAh, panAl, s);
    kB3  <<<dim3(8, 32), 256, 0, stream>>>(panAh, panAl,
                                           panBh3 + (size_t)s*1114112,
                                           panBl3 + (size_t)s*1114112,
                                           as_ + (size_t)s*4194304);
  }
  for (int s = 0; s < 3; ++s) {
    kL3 <<<dim3(16, 32), 256, 0, stream>>>(cxh, cxl, lwh, lwl, L_b, w_, lt, s);
    kLLT<<<dim3(1024),   128, 0, stream>>>(lt, as_, s);
  }
  kC12<<<dim3(4096),    64, 0, stream>>>(as_, q2, z0, out);
}

// Round 14
// 544.953 us; speedup vs baseline: 1.2708x; 1.1488x over previous
//
#include <hip/hip_runtime.h>
#include <math.h>

// TVKoopmanMoE: B=4096, C=128, D=32, K=8, R=8, NSEG=3, STEPS=8 each, DT=0.1
//  - kA: gates w (softmax) + diag^2
//  - kT/kCvtB: V2^T hi/lo bf16 panels (coalesced)
//  - kB3: AS = Shat GEMM via MFMA bf16 hi/lo (bias folded via K-ext)
//  - kL4: Ltil GEMM via MFMA; writes LtilT bf16 hi/lo panels [b][32 d][64 kr]
//  - kC13 (per segment): LLT = MM(P,P) via MFMA folded into init (kLLT deleted),
//    frob clamp, Taylor ORDER=4 + 2 squarings + 8-step propagation.
//    z/cov state chains between segment launches through the output buffer.

#define NSEGC 3
#define BSZ   4096
#define MUC   0.14861455999447191f   /* -ln(0.7)/(0.1*24) */
#define XSC   0.025f                 /* DT / 2^SQ = 0.1/4 */
#define XRS(r) (((r) & 7) << 2)

typedef unsigned short ushort_t;
typedef unsigned int uint_t;
typedef __attribute__((ext_vector_type(8))) short bf16x8;
typedef __attribute__((ext_vector_type(16))) float f32x16;

__device__ __forceinline__ void ld4(float d[4], const float* p) {
  const float4 v = *(const float4*)p; d[0]=v.x; d[1]=v.y; d[2]=v.z; d[3]=v.w;
}
__device__ __forceinline__ void st4(float* p, const float d[4]) {
  *(float4*)p = make_float4(d[0], d[1], d[2], d[3]);
}
__device__ __forceinline__ unsigned short bf_rne(float x) {
  unsigned b = __float_as_uint(x);
  unsigned r = b + 0x7FFFu + ((b >> 16) & 1u);
  return (unsigned short)(r >> 16);
}
__device__ __forceinline__ float bf2f(short v) {
  return __uint_as_float(((uint_t)(unsigned short)v) << 16);
}

// ---------------- kA: gates (softmax(logits/2)) and diag^2 ----------------
__global__ __launch_bounds__(64) void kA(const float* __restrict__ ctx,
    const float* __restrict__ GW, const float* __restrict__ Gb,
    const float* __restrict__ SgW, const float* __restrict__ Sgb,
    float* __restrict__ Wsm, float* __restrict__ Q2) {
  const int b = blockIdx.x, s = blockIdx.y, l = threadIdx.x;
  __shared__ float c[128];
  c[l]      = ctx[(size_t)b*128 + l];
  c[l + 64] = ctx[(size_t)b*128 + 64 + l];
  __syncthreads();
  if (l < 8) {
    float acc = Gb[s*8 + l];
    #pragma unroll 4
    for (int q = 0; q < 128; ++q) acc += c[q] * GW[(size_t)(s*128 + q)*8 + l];
    float li = acc * 0.5f;            // / TEMP (=2)
    float m = li;
    m = fmaxf(m, __shfl_xor(m, 1));
    m = fmaxf(m, __shfl_xor(m, 2));
    m = fmaxf(m, __shfl_xor(m, 4));
    float e = expf(li - m);
    float sum = e;
    sum += __shfl_xor(sum, 1);
    sum += __shfl_xor(sum, 2);
    sum += __shfl_xor(sum, 4);
    Wsm[((size_t)s*BSZ + b)*8 + l] = e / sum;
  } else if (l < 40) {
    const int d = l - 8;
    float acc = Sgb[s*32 + d];
    #pragma unroll 4
    for (int q = 0; q < 128; ++q) acc += c[q] * SgW[(size_t)(s*128 + q)*32 + d];
    float sp = fmaxf(acc, 0.f) + log1pf(expf(-fabsf(acc)));  // stable softplus
    float dg = fminf(sp, 1.0f);
    Q2[((size_t)s*BSZ + b)*32 + d] = dg * dg;
  }
}

// -------- kT: SWT[(s*1024+kc)*1024 + n] = M_{s,c,k}[(n&31)*32 + (n>>5)] ------
__global__ __launch_bounds__(256) void kT(const float* __restrict__ SW,
                                          float* __restrict__ SWT) {
  __shared__ float mt[1056];   // 32 rows x 33
  const int kc = blockIdx.x, s = blockIdx.y, t = threadIdx.x;
  const int k = kc >> 7, c = kc & 127;
  const float* src = SW + ((size_t)(s*128 + c))*8192 + (size_t)k*1024;
  float* dst = SWT + ((size_t)s*1024 + kc)*1024;
  for (int i = t; i < 1024; i += 256) mt[(i >> 5)*33 + (i & 31)] = src[i];
  __syncthreads();
  for (int i = t; i < 1024; i += 256) dst[i] = mt[(i & 31)*33 + (i >> 5)];
}

// -------- kCvtB: B'[s][n][kc] hi/lo bf16, coalesced (16-n groups) -----------
__global__ __launch_bounds__(256) void kCvtB(const float* __restrict__ SW,
    const float* __restrict__ SWT, const float* __restrict__ Sb,
    ushort_t* __restrict__ Bh, ushort_t* __restrict__ Bl) {
  const int s = blockIdx.y, t = threadIdx.x;
  const int n0 = blockIdx.x * 16;
  const int tn = t & 15, tck = t >> 4;
  const int n = n0 + tn;
  const int nT = (n & 31)*32 + (n >> 5);
  ushort_t* bh = Bh + (size_t)s*1114112;
  ushort_t* bl = Bl + (size_t)s*1114112;
  for (int kc0 = 0; kc0 < 1088; kc0 += 16) {
    const int kc = kc0 + tck;
    float v = 0.f;
    if (kc < 1024) {
      const int k = kc >> 7, c = kc & 127;
      v = SW[((size_t)(s*128 + c))*8192 + (size_t)k*1024 + n]
        - SWT[((size_t)s*1024 + kc)*1024 + n];
    } else if (kc < 1032) {
      const int k2 = kc - 1024;
      const float* base = Sb + (size_t)s*8192 + (size_t)k2*1024;
      v = base[n] - base[nT];
    }
    const unsigned short h = bf_rne(v);
    bh[(size_t)n*1088 + kc] = h;
    bl[(size_t)n*1088 + kc] = bf_rne(v - __uint_as_float(((unsigned)h) << 16));
  }
}

// -------- kCvtX: ctx -> hi/lo bf16 panels [4096][128] ----------------------
__global__ __launch_bounds__(256) void kCvtX(const float* __restrict__ ctx,
    ushort_t* __restrict__ Xh, ushort_t* __restrict__ Xl) {
  const int idx = blockIdx.x*256 + threadIdx.x;
  const float v = ctx[idx];
  const unsigned short h = bf_rne(v);
  Xh[idx] = h;
  Xl[idx] = bf_rne(v - __uint_as_float(((unsigned)h) << 16));
}

// -------- kCvtL: lwT[s][n][c] = L_W[s][c][n] hi/lo bf16 --------------------
__global__ __launch_bounds__(256) void kCvtL(const float* __restrict__ LW,
    ushort_t* __restrict__ Lh, ushort_t* __restrict__ Ll) {
  __shared__ float tile[32][33];
  const int nb = blockIdx.x * 32, cb = blockIdx.y * 32, s = blockIdx.z;
  const int tx = threadIdx.x & 31, ty = threadIdx.x >> 5;
  for (int r = ty; r < 32; r += 8)
    tile[r][tx] = LW[((size_t)(s*128 + cb + r))*2048 + nb + tx];
  __syncthreads();
  for (int r = ty; r < 32; r += 8) {
    const float v = tile[tx][r];          // LW[cb+tx][nb+r]
    const unsigned short h = bf_rne(v);
    const size_t o = ((size_t)s*2048 + nb + r)*128 + cb + tx;
    Lh[o] = h;
    Ll[o] = bf_rne(v - __uint_as_float(((unsigned)h) << 16));
  }
}

// -------- kCvtA: A'[b][kc] hi/lo bf16; kc<1024: w[k]*ctx[c]; 1024..1031: w ---
__global__ __launch_bounds__(256) void kCvtA(const float* __restrict__ ctx,
    const float* __restrict__ Wsm, ushort_t* __restrict__ Ah,
    ushort_t* __restrict__ Al, int s) {
  __shared__ float cs[128];
  __shared__ float wwv[8];
  const int b = blockIdx.x, t = threadIdx.x;
  if (t < 128) cs[t] = ctx[(size_t)b*128 + t];
  else if (t < 136) wwv[t - 128] = Wsm[((size_t)s*BSZ + b)*8 + (t - 128)];
  __syncthreads();
  for (int kc = t; kc < 1088; kc += 256) {
    float v = 0.f;
    if (kc < 1024) v = wwv[kc >> 7] * cs[kc & 127];
    else if (kc < 1032) v = wwv[kc - 1024];
    const unsigned short h = bf_rne(v);
    const float hf = __uint_as_float(((unsigned)h) << 16);
    Ah[(size_t)b*1088 + kc] = h;
    Al[(size_t)b*1088 + kc] = bf_rne(v - hf);
  }
}

// -------- kB3: AS_seg = A' @ B'^T via 32x32x16 bf16 MFMA, 3-product hi/lo ----
__global__ __launch_bounds__(256) void kB3(const ushort_t* __restrict__ Ah,
    const ushort_t* __restrict__ Al, const ushort_t* __restrict__ Bh,
    const ushort_t* __restrict__ Bl, float* __restrict__ ASseg) {
  __shared__ ushort_t sArr[2][2][8192];   // [buf][A/B][128 rows x 64 cols]
  const int t = threadIdx.x;
  const int l = t & 63, w = t >> 6;
  const int hh = l >> 5, lane31 = l & 31;
  const int nb = blockIdx.x * 128, bb = blockIdx.y * 128;
  const int wr0 = (w & 1) * 64, wc0 = (w >> 1) * 64;

  const ushort_t* APT[3] = {Ah, Ah, Al};
  const ushort_t* BPT[3] = {Bh, Bl, Bh};

  f32x16 acc[2][2];
  #pragma unroll
  for (int a = 0; a < 2; ++a)
    #pragma unroll
    for (int bq = 0; bq < 2; ++bq)
      #pragma unroll
      for (int e = 0; e < 16; ++e) acc[a][bq][e] = 0.f;

  #define STAGE(buf, it) do {                                                  \
    const int p_ = (it) / 17, ks_ = (it) - p_*17;                              \
    const ushort_t* As_ = APT[p_];                                             \
    const ushort_t* Bs_ = BPT[p_];                                             \
    _Pragma("unroll")                                                          \
    for (int i_ = 0; i_ < 4; ++i_) {                                           \
      const int gidx_ = i_*256 + t;                                            \
      const int r_ = gidx_ >> 3, g_ = gidx_ & 7;                               \
      const int gs_ = g_ ^ (r_ & 7);                                           \
      const ushort_t* srcA_ = As_ + (size_t)(bb + r_)*1088 + ks_*64 + gs_*8;   \
      const ushort_t* srcB_ = Bs_ + (size_t)(nb + r_)*1088 + ks_*64 + gs_*8;   \
      __builtin_amdgcn_global_load_lds(                                        \
        (const __attribute__((address_space(1))) unsigned int*)srcA_,          \
        (__attribute__((address_space(3))) unsigned int*)&sArr[buf][0][(i_*256 + w*64)*8], \
        16, 0, 0);                                                             \
      __builtin_amdgcn_global_load_lds(                                        \
        (const __attribute__((address_space(1))) unsigned int*)srcB_,          \
        (__attribute__((address_space(3))) unsigned int*)&sArr[buf][1][(i_*256 + w*64)*8], \
        16, 0, 0);                                                             \
    }                                                                          \
  } while (0)

  STAGE(0, 0);
  int cur = 0;
  #pragma unroll 1
  for (int it = 0; it < 51; ++it) {
    __syncthreads();                      // drain loads into buf[cur]
    if (it + 1 < 51) STAGE(cur ^ 1, it + 1);
    const ushort_t* lA = &sArr[cur][0][0];
    const ushort_t* lB = &sArr[cur][1][0];
    #pragma unroll
    for (int kc = 0; kc < 4; ++kc) {
      bf16x8 af[2], bfr[2];
      #pragma unroll
      for (int rt = 0; rt < 2; ++rt) {
        const int row = wr0 + rt*32 + lane31;
        const int slot = (kc*2 + hh) ^ (row & 7);
        af[rt] = *(const bf16x8*)&lA[row*64 + slot*8];
      }
      #pragma unroll
      for (int ct = 0; ct < 2; ++ct) {
        const int row = wc0 + ct*32 + lane31;
        const int slot = (kc*2 + hh) ^ (row & 7);
        bfr[ct] = *(const bf16x8*)&lB[row*64 + slot*8];
      }
      #pragma unroll
      for (int rt = 0; rt < 2; ++rt)
        #pragma unroll
        for (int ct = 0; ct < 2; ++ct)
          acc[rt][ct] = __builtin_amdgcn_mfma_f32_32x32x16_bf16(
              af[rt], bfr[ct], acc[rt][ct], 0, 0, 0);
    }
    cur ^= 1;
  }
  #undef STAGE

  #pragma unroll
  for (int rt = 0; rt < 2; ++rt)
    #pragma unroll
    for (int ct = 0; ct < 2; ++ct) {
      float* o = ASseg + ((size_t)(bb + wr0 + rt*32))*1024 + nb + wc0 + ct*32 + lane31;
      #pragma unroll
      for (int reg = 0; reg < 16; ++reg) {
        const int row = (reg & 3) + 8*(reg >> 2) + 4*hh;
        o[(size_t)row*1024] = acc[rt][ct][reg];
      }
    }
}

// -------- kL4: LtilT bf16 hi/lo panels [b][32 d][64 kr] via MFMA (K=128) ----
__global__ __launch_bounds__(256) void kL4(const ushort_t* __restrict__ Xh,
    const ushort_t* __restrict__ Xl, const ushort_t* __restrict__ Lh,
    const ushort_t* __restrict__ Ll, const float* __restrict__ Lb,
    const float* __restrict__ Wsm, ushort_t* __restrict__ LTh,
    ushort_t* __restrict__ LTl, int s) {
  __shared__ ushort_t sArr[2][2][8192];
  __shared__ float sqw[128][8];
  const int t = threadIdx.x;
  const int l = t & 63, w = t >> 6;
  const int hh = l >> 5, lane31 = l & 31;
  const int nb = blockIdx.x * 128, bb = blockIdx.y * 128;
  const int wr0 = (w & 1) * 64, wc0 = (w >> 1) * 64;
  for (int i = t; i < 1024; i += 256)
    sqw[i >> 3][i & 7] = sqrtf(Wsm[((size_t)s*BSZ + bb + (i >> 3))*8 + (i & 7)]);

  const ushort_t* APT[3] = {Xh, Xh, Xl};
  const ushort_t* BPT[3] = {Lh + (size_t)s*262144, Ll + (size_t)s*262144,
                            Lh + (size_t)s*262144};

  f32x16 acc[2][2];
  #pragma unroll
  for (int a = 0; a < 2; ++a)
    #pragma unroll
    for (int bq = 0; bq < 2; ++bq)
      #pragma unroll
      for (int e = 0; e < 16; ++e) acc[a][bq][e] = 0.f;

  #define STAGEL(buf, it) do {                                                 \
    const int p_ = (it) >> 1, ks_ = (it) & 1;                                  \
    const ushort_t* As_ = APT[p_];                                             \
    const ushort_t* Bs_ = BPT[p_];                                             \
    _Pragma("unroll")                                                          \
    for (int i_ = 0; i_ < 4; ++i_) {                                           \
      const int gidx_ = i_*256 + t;                                            \
      const int r_ = gidx_ >> 3, g_ = gidx_ & 7;                               \
      const int gs_ = g_ ^ (r_ & 7);                                           \
      const ushort_t* srcA_ = As_ + (size_t)(bb + r_)*128 + ks_*64 + gs_*8;    \
      const ushort_t* srcB_ = Bs_ + (size_t)(nb + r_)*128 + ks_*64 + gs_*8;    \
      __builtin_amdgcn_global_load_lds(                                        \
        (const __attribute__((address_space(1))) unsigned int*)srcA_,          \
        (__attribute__((address_space(3))) unsigned int*)&sArr[buf][0][(i_*256 + w*64)*8], \
        16, 0, 0);                                                             \
      __builtin_amdgcn_global_load_lds(                                        \
        (const __attribute__((address_space(1))) unsigned int*)srcB_,          \
        (__attribute__((address_space(3))) unsigned int*)&sArr[buf][1][(i_*256 + w*64)*8], \
        16, 0, 0);                                                             \
    }                                                                          \
  } while (0)

  STAGEL(0, 0);
  int cur = 0;
  #pragma unroll 1
  for (int it = 0; it < 6; ++it) {
    __syncthreads();
    if (it + 1 < 6) STAGEL(cur ^ 1, it + 1);
    const ushort_t* lA = &sArr[cur][0][0];
    const ushort_t* lB = &sArr[cur][1][0];
    #pragma unroll
    for (int kc = 0; kc < 4; ++kc) {
      bf16x8 af[2], bfr[2];
      #pragma unroll
      for (int rt = 0; rt < 2; ++rt) {
        const int row = wr0 + rt*32 + lane31;
        const int slot = (kc*2 + hh) ^ (row & 7);
        af[rt] = *(const bf16x8*)&lA[row*64 + slot*8];
      }
      #pragma unroll
      for (int ct = 0; ct < 2; ++ct) {
        const int row = wc0 + ct*32 + lane31;
        const int slot = (kc*2 + hh) ^ (row & 7);
        bfr[ct] = *(const bf16x8*)&lB[row*64 + slot*8];
      }
      #pragma unroll
      for (int rt = 0; rt < 2; ++rt)
        #pragma unroll
        for (int ct = 0; ct < 2; ++ct)
          acc[rt][ct] = __builtin_amdgcn_mfma_f32_32x32x16_bf16(
              af[rt], bfr[ct], acc[rt][ct], 0, 0, 0);
    }
    cur ^= 1;
  }
  #undef STAGEL

  // epilogue: v=(acc+Lb[n])*sqrt(w[b][k]); LtilT[b][d][kr=k*8+r] hi/lo bf16
  #pragma unroll
  for (int rt = 0; rt < 2; ++rt)
    #pragma unroll
    for (int ct = 0; ct < 2; ++ct) {
      const int n = nb + wc0 + ct*32 + lane31;   // n = k*256 + d*8 + r
      const float lb = Lb[(size_t)s*2048 + n];
      const int kidx = n >> 8;
      const int d = (n >> 3) & 31, r = n & 7;
      const size_t coloff = (size_t)d*64 + kidx*8 + r;
      #pragma unroll
      for (int reg = 0; reg < 16; ++reg) {
        const int lrow = wr0 + rt*32 + (reg & 3) + 8*(reg >> 2) + 4*hh;
        const float v = (acc[rt][ct][reg] + lb) * sqw[lrow][kidx];
        const unsigned short h = bf_rne(v);
        const size_t o = (size_t)(bb + lrow)*2048 + coloff;
        LTh[o] = h;
        LTl[o] = bf_rne(v - __uint_as_float(((unsigned)h) << 16));
      }
    }
}

// ================= kC13: per-seg MFMA expm + propagation, LLT folded ==========
struct Frag { bf16x8 h0, l0, h1, l1; };

__device__ __forceinline__ void cvt8(const float x[8], bf16x8& hi, bf16x8& lo) {
  uint_t h[4], l[4];
  #pragma unroll
  for (int p = 0; p < 4; ++p) {
    const uint_t b0 = __float_as_uint(x[2*p]);
    const uint_t b1 = __float_as_uint(x[2*p + 1]);
    h[p] = __builtin_amdgcn_perm(b1, b0, 0x07060302u);
    const float l0f = x[2*p]     - __uint_as_float(b0 & 0xFFFF0000u);  // exact
    const float l1f = x[2*p + 1] - __uint_as_float(b1 & 0xFFFF0000u);  // exact
    l[p] = __builtin_amdgcn_perm(__float_as_uint(l1f), __float_as_uint(l0f),
                                 0x07060302u);
  }
  hi = __builtin_bit_cast(bf16x8, make_uint4(h[0], h[1], h[2], h[3]));
  lo = __builtin_bit_cast(bf16x8, make_uint4(l[0], l[1], l[2], l[3]));
}
__device__ __forceinline__ void rd_row8(const float* M, int r, int kb, float o[8]) {
  const float* p = M + r*32;
  ld4(o,     p + ((kb)     ^ XRS(r)));
  ld4(o + 4, p + ((kb + 4) ^ XRS(r)));
}
__device__ __forceinline__ void rd_col8(const float* M, int c, int kb, float o[8]) {
  #pragma unroll
  for (int e = 0; e < 8; ++e) o[e] = M[(kb + e)*32 + (c ^ XRS(kb + e))];
}
__device__ __forceinline__ void mkfrag_row(const float* M, int r, int hoff, Frag& f) {
  float t0[8], t1[8];
  rd_row8(M, r, hoff, t0);
  rd_row8(M, r, 16 + hoff, t1);
  cvt8(t0, f.h0, f.l0);
  cvt8(t1, f.h1, f.l1);
}
__device__ __forceinline__ void mkfrag_col(const float* M, int c, int hoff, Frag& f) {
  float t0[8], t1[8];
  rd_col8(M, c, hoff, t0);
  rd_col8(M, c, 16 + hoff, t1);
  cvt8(t0, f.h0, f.l0);
  cvt8(t1, f.h1, f.l1);
}
__device__ __forceinline__ f32x16 mmacc(const Frag& A, const Frag& B, f32x16 acc) {
  acc = __builtin_amdgcn_mfma_f32_32x32x16_bf16(A.h0, B.h0, acc, 0, 0, 0);
  acc = __builtin_amdgcn_mfma_f32_32x32x16_bf16(A.h0, B.l0, acc, 0, 0, 0);
  acc = __builtin_amdgcn_mfma_f32_32x32x16_bf16(A.l0, B.h0, acc, 0, 0, 0);
  acc = __builtin_amdgcn_mfma_f32_32x32x16_bf16(A.h1, B.h1, acc, 0, 0, 0);
  acc = __builtin_amdgcn_mfma_f32_32x32x16_bf16(A.h1, B.l1, acc, 0, 0, 0);
  acc = __builtin_amdgcn_mfma_f32_32x32x16_bf16(A.l1, B.h1, acc, 0, 0, 0);
  return acc;
}
__device__ __forceinline__ f32x16 zero16() {
  f32x16 z = {0.f,0.f,0.f,0.f,0.f,0.f,0.f,0.f,0.f,0.f,0.f,0.f,0.f,0.f,0.f,0.f};
  return z;
}
__device__ __forceinline__ void st_T(float* M, int j, int ho4, const float v[16]) {
  float* p = M + j*32;
  #pragma unroll
  for (int m = 0; m < 4; ++m) st4(p + ((8*m + ho4) ^ XRS(j)), v + 4*m);
}
__device__ __forceinline__ void ld16_T(const float* M, int j, int ho4, float o[16]) {
  const float* p = M + j*32;
  #pragma unroll
  for (int m = 0; m < 4; ++m) ld4(o + 4*m, p + ((8*m + ho4) ^ XRS(j)));
}

__global__ __launch_bounds__(64, 3) void kC13(const float* __restrict__ AS,
    const float* __restrict__ Q2, const float* __restrict__ z0,
    const ushort_t* __restrict__ LTh, const ushort_t* __restrict__ LTl,
    float* __restrict__ out, int s) {
  __shared__ float S11[1024];  // R11^T (Phi^T) ; G scratch in propagation
  __shared__ float S12[1024];  // a staging; R12^T (E12^T); cov buffer
  __shared__ float S22[1024];  // R22^T ; later Qd
  __shared__ float zarr[32], qds[32];
  const int b = blockIdx.x, t = threadIdx.x;
  const int j = t & 31, hh = t >> 5;
  const int hoff = hh * 8, ho4 = hh * 4;

  float* covout = out + 3145728 + (size_t)b*24576;
  float* stout  = out + (size_t)b*768;

  // ---- state init: z, cov (chained through the output buffer) ----
  if (t < 32) {
    zarr[t] = (s == 0) ? z0[(size_t)b*32 + t] : stout[(8*s - 1)*32 + t];
    qds[t] = Q2[((size_t)s*BSZ + b)*32 + t] * XSC;
  }
  float covreg[16];
  if (s == 0) {
    #pragma unroll
    for (int r = 0; r < 16; ++r) covreg[r] = 0.f;
  } else {
    const float* cbp = covout + (size_t)(8*s - 1)*1024;
    #pragma unroll
    for (int r = 0; r < 16; ++r)
      covreg[r] = cbp[((r&3) + 8*(r>>2) + ho4)*32 + j];
  }

  // ---- LLT = LtilT @ LtilT^T via MFMA (A-frag == B-frag, K=64) ----
  f32x16 llt = zero16();
  {
    const ushort_t* ph = LTh + (size_t)b*2048 + j*64 + hoff;
    const ushort_t* pl = LTl + (size_t)b*2048 + j*64 + hoff;
    Frag FA, FB;
    FA.h0 = *(const bf16x8*)&ph[0];  FA.l0 = *(const bf16x8*)&pl[0];
    FA.h1 = *(const bf16x8*)&ph[16]; FA.l1 = *(const bf16x8*)&pl[16];
    FB.h0 = *(const bf16x8*)&ph[32]; FB.l0 = *(const bf16x8*)&pl[32];
    FB.h1 = *(const bf16x8*)&ph[48]; FB.l1 = *(const bf16x8*)&pl[48];
    llt = mmacc(FA, FA, llt);
    llt = mmacc(FB, FB, llt);
  }

  // ---- A tile (pattern [j][8m+ho4+e]), -LLT, -muI, frob clamp, scale -------
  const float* asb = AS + ((size_t)s*BSZ + b)*1024;
  float av[16];
  #pragma unroll
  for (int m = 0; m < 4; ++m) ld4(av + 4*m, &asb[j*32 + 8*m + ho4]);
  #pragma unroll
  for (int r = 0; r < 16; ++r) {
    av[r] -= llt[r];                    // LLT[col(r)][j] == LLT[j][col(r)]
    const int col = (r & 3) + 8*(r >> 2) + ho4;
    if (col == j) av[r] -= MUC;
  }
  float ssq = 0.f;
  #pragma unroll
  for (int r = 0; r < 16; ++r) ssq += av[r]*av[r];
  #pragma unroll
  for (int off = 1; off < 64; off <<= 1) ssq += __shfl_xor(ssq, off);
  const float frob = sqrtf(ssq);
  const float sc = (frob > 3.0f ? 3.0f / (frob + 1e-6f) : 1.0f) * XSC;
  #pragma unroll
  for (int r = 0; r < 16; ++r) av[r] *= sc;
  __syncthreads();
  #pragma unroll
  for (int m = 0; m < 4; ++m)
    st4(&S12[j*32 + ((8*m + ho4) ^ XRS(j))], av + 4*m);  // S12 = a (row j)
  __syncthreads();
  Frag aA, aT;
  mkfrag_row(S12, j, hoff, aA);   // A-frag of a
  mkfrag_col(S12, j, hoff, aT);   // A-frag of a^T
  __syncthreads();
  #pragma unroll
  for (int m = 0; m < 4; ++m) {
    float id[4], zo[4] = {0.f, 0.f, 0.f, 0.f};
    #pragma unroll
    for (int e = 0; e < 4; ++e) id[e] = (16*hh + 4*m + e == j) ? 1.f : 0.f;
    st4(&S11[j*32 + ((16*hh + 4*m) ^ XRS(j))], id);
    st4(&S22[j*32 + ((16*hh + 4*m) ^ XRS(j))], id);
    st4(&S12[j*32 + ((16*hh + 4*m) ^ XRS(j))], zo);
  }
  __syncthreads();
  float qv[16];
  #pragma unroll
  for (int r = 0; r < 16; ++r) qv[r] = qds[(r&3) + 8*(r>>2) + ho4];

  // ---- Taylor Horner ORDER=4 on X=[[a,q],[0,-a^T]] (transposed blocks) ----
  for (int k = 4; k >= 1; --k) {
    const float rk = 1.0f / (float)k;
    Frag Bf;
    float Xs[16];
    mkfrag_row(S11, j, hoff, Bf);
    f32x16 X = mmacc(aA, Bf, zero16());
    #pragma unroll
    for (int r = 0; r < 16; ++r) {
      const int row = (r&3) + 8*(r>>2) + ho4;
      Xs[r] = X[r]*rk + (row == j ? 1.f : 0.f);
    }
    st_T(S11, j, ho4, Xs);
    mkfrag_row(S12, j, hoff, Bf);
    X = mmacc(aA, Bf, zero16());
    float rv[16];
    ld16_T(S22, j, ho4, rv);
    #pragma unroll
    for (int r = 0; r < 16; ++r) Xs[r] = (X[r] + qv[r]*rv[r]) * rk;
    st_T(S12, j, ho4, Xs);
    mkfrag_row(S22, j, hoff, Bf);
    X = mmacc(aT, Bf, zero16());
    #pragma unroll
    for (int r = 0; r < 16; ++r) {
      const int row = (r&3) + 8*(r>>2) + ho4;
      Xs[r] = (row == j ? 1.f : 0.f) - X[r]*rk;
    }
    st_T(S22, j, ho4, Xs);
  }
  __syncthreads();

  // ---- squaring 0 ----
  {
    Frag Ac, Br;
    float Xs[16];
    mkfrag_col(S11, j, hoff, Ac);
    mkfrag_row(S11, j, hoff, Br);
    f32x16 X1 = mmacc(Ac, Br, zero16());
    #pragma unroll
    for (int r = 0; r < 16; ++r) Xs[r] = X1[r];
    st_T(S11, j, ho4, Xs);
    Frag B12; mkfrag_row(S12, j, hoff, B12);
    f32x16 X2 = mmacc(Ac, B12, zero16());
    Frag A12; mkfrag_col(S12, j, hoff, A12);
    Frag B22; mkfrag_row(S22, j, hoff, B22);
    X2 = mmacc(A12, B22, X2);
    #pragma unroll
    for (int r = 0; r < 16; ++r) Xs[r] = X2[r];
    st_T(S12, j, ho4, Xs);
    Frag A22; mkfrag_col(S22, j, hoff, A22);
    f32x16 X3 = mmacc(A22, B22, zero16());
    #pragma unroll
    for (int r = 0; r < 16; ++r) Xs[r] = X3[r];
    st_T(S22, j, ho4, Xs);
  }
  __syncthreads();
  // ---- squaring 1: R11, R12 only ----
  {
    Frag Ac, Br;
    float Xs[16];
    mkfrag_col(S11, j, hoff, Ac);
    mkfrag_row(S11, j, hoff, Br);
    f32x16 X1 = mmacc(Ac, Br, zero16());
    Frag B12; mkfrag_row(S12, j, hoff, B12);
    f32x16 X2 = mmacc(Ac, B12, zero16());
    Frag A12; mkfrag_col(S12, j, hoff, A12);
    Frag B22; mkfrag_row(S22, j, hoff, B22);
    X2 = mmacc(A12, B22, X2);
    #pragma unroll
    for (int r = 0; r < 16; ++r) Xs[r] = X1[r];
    st_T(S11, j, ho4, Xs);
    #pragma unroll
    for (int r = 0; r < 16; ++r) Xs[r] = X2[r];
    st_T(S12, j, ho4, Xs);
  }
  __syncthreads();

  // ---- Qd = 0.5*(Phi@E12 + (Phi@E12)^T) -> S22 ----
  Frag PhiF;
  mkfrag_col(S11, j, hoff, PhiF);
  {
    Frag B12; mkfrag_row(S12, j, hoff, B12);
    f32x16 Xq = mmacc(PhiF, B12, zero16());
    float Xs[16];
    #pragma unroll
    for (int r = 0; r < 16; ++r) Xs[r] = Xq[r];
    st_T(S22, j, ho4, Xs);
    __syncthreads();
    float sym[16];
    #pragma unroll
    for (int r = 0; r < 16; ++r) {
      const int row = (r&3) + 8*(r>>2) + ho4;
      const float tv = S22[row*32 + (j ^ XRS(row))];
      sym[r] = 0.5f * (Xs[r] + tv);
    }
    __syncthreads();
    st_T(S22, j, ho4, sym);
  }
  __syncthreads();

  // ---- stage cov (covreg, C/D order) into S12 (E12 dead) ----
  st_T(S12, j, ho4, covreg);
  __syncthreads();

  // ---- 8 propagation steps: cov <- Phi cov Phi^T + Qd ; z <- Phi z ----
  for (int tt = 0; tt < 8; ++tt) {
    Frag Bcov; mkfrag_row(S12, j, hoff, Bcov);
    f32x16 G = mmacc(PhiF, Bcov, zero16());
    float Gs[16];
    #pragma unroll
    for (int r = 0; r < 16; ++r) Gs[r] = G[r];
    st_T(S11, j, ho4, Gs);                         // S11 = G^T (Phi in regs)
    Frag AG; mkfrag_col(S11, j, hoff, AG);
    f32x16 C = mmacc(AG, PhiF, zero16());
    float qdv[16], Cs[16];
    ld16_T(S22, j, ho4, qdv);
    #pragma unroll
    for (int r = 0; r < 16; ++r) Cs[r] = C[r] + qdv[r];
    float zp = 0.f;
    #pragma unroll
    for (int e = 0; e < 8; ++e) {
      zp += (bf2f(PhiF.h0[e]) + bf2f(PhiF.l0[e])) * zarr[hoff + e];
      zp += (bf2f(PhiF.h1[e]) + bf2f(PhiF.l1[e])) * zarr[16 + hoff + e];
    }
    zp += __shfl_xor(zp, 32);
    st_T(S12, j, ho4, Cs);
    float* cb = covout + (size_t)(s*8 + tt)*1024;
    #pragma unroll
    for (int r = 0; r < 16; ++r)
      cb[((r&3) + 8*(r>>2) + ho4)*32 + j] = Cs[r];
    if (t < 32) {
      zarr[t] = zp;
      stout[(s*8 + tt)*32 + t] = zp;
    }
    __syncthreads();
  }
}

// ---------------- launch ----------------
extern "C" void kernel_launch(void* const* d_in, const int* in_sizes, int n_in,
                              void* d_out, int out_size, void* d_ws, size_t ws_size,
                              hipStream_t stream) {
  const float* ctx  = (const float*)d_in[0];
  const float* z0   = (const float*)d_in[1];
  const float* S_W  = (const float*)d_in[2];
  const float* S_b  = (const float*)d_in[3];
  const float* L_W  = (const float*)d_in[4];
  const float* L_b  = (const float*)d_in[5];
  const float* G_W  = (const float*)d_in[6];
  const float* G_b  = (const float*)d_in[7];
  const float* Sg_W = (const float*)d_in[8];
  const float* Sg_b = (const float*)d_in[9];
  float* out = (float*)d_out;
  float* ws  = (float*)d_ws;

  // ws layout (f32 offsets):
  //   w_ 0 | q2 98304 | as_ 1015808 (12.6M f32) -> 13598720
  //   SWT (3.1M f32) ALIASES as_ head (dead before kB3 writes as_)
  //   phase1 panels (ushort) @13598720: Ah/Al/Bh3/Bl3 -> f32 21397504
  //   LTh/LTl (16.8M ushort) ALIAS panels @13598720 (written after all kB3)
  //   cx/lwT panels (ushort) @21987328 -> ends f32 23298048 (93.2 MB)
  float* w_   = ws;
  float* q2   = ws + 98304;
  float* as_  = ws + 1015808;
  float* swt  = ws + 1015808;          // aliases as_ head; dead before kB3
  ushort_t* panAh  = (ushort_t*)(ws + 13598720);
  ushort_t* panAl  = panAh + 4456448;
  ushort_t* panBh3 = panAl + 4456448;
  ushort_t* panBl3 = panBh3 + 3342336;
  ushort_t* LTh = (ushort_t*)(ws + 13598720);   // aliases A/B panels (post-kB3)
  ushort_t* LTl = LTh + 8388608;
  ushort_t* cxh = (ushort_t*)(ws + 21987328);
  ushort_t* cxl = cxh + 524288;
  ushort_t* lwh = cxl + 524288;
  ushort_t* lwl = lwh + 786432;

  kA   <<<dim3(4096, 3), 64,  0, stream>>>(ctx, G_W, G_b, Sg_W, Sg_b, w_, q2);
  kCvtX<<<dim3(2048),    256, 0, stream>>>(ctx, cxh, cxl);
  kCvtL<<<dim3(64, 4, 3),256, 0, stream>>>(L_W, lwh, lwl);
  kT   <<<dim3(1024, 3), 256, 0, stream>>>(S_W, swt);
  kCvtB<<<dim3(64, 3),   256, 0, stream>>>(S_W, swt, S_b, panBh3, panBl3);
  for (int s = 0; s < 3; ++s) {
    kCvtA<<<dim3(4096), 256, 0, stream>>>(ctx, w_, panAh, panAl, s);
    kB3  <<<dim3(8, 32), 256, 0, stream>>>(panAh, panAl,
                                           panBh3 + (size_t)s*1114112,
                                           panBl3 + (size_t)s*1114112,
                                           as_ + (size_t)s*4194304);
  }
  for (int s = 0; s < 3; ++s) {
    kL4 <<<dim3(16, 32), 256, 0, stream>>>(cxh, cxl, lwh, lwl, L_b, w_,
                                           LTh, LTl, s);
    kC13<<<dim3(4096),   64,  0, stream>>>(as_, q2, z0, LTh, LTl, out, s);
  }
}

// Round 15
// 542.207 us; speedup vs baseline: 1.2772x; 1.0051x over previous
//
#include <hip/hip_runtime.h>
#include <math.h>

// TVKoopmanMoE: B=4096, C=128, D=32, K=8, R=8, NSEG=3, STEPS=8 each, DT=0.1
//  - kA: gates w (softmax) + diag^2
//  - kT/kCvtB: V2^T hi/lo bf16 panels (coalesced)
//  - kB3: AS = Shat GEMM via MFMA bf16 hi/lo (bias folded via K-ext)
//  - kL4: Ltil GEMM via MFMA; writes LtilT bf16 hi/lo panels [b][32 d][64 kr]
//  - kC14 (per segment): LLT folded via MFMA; Taylor ORDER=4 + 2 squarings +
//    8-step propagation. Propagation reassociated as H=cov@Phi^T, cov'=Phi@H
//    so BOTH frag builds are row reads (no 16-scalar col read on the critical
//    path); Qd frag hoisted out of the loop.

#define NSEGC 3
#define BSZ   4096
#define MUC   0.14861455999447191f   /* -ln(0.7)/(0.1*24) */
#define XSC   0.025f                 /* DT / 2^SQ = 0.1/4 */
#define XRS(r) (((r) & 7) << 2)

typedef unsigned short ushort_t;
typedef unsigned int uint_t;
typedef __attribute__((ext_vector_type(8))) short bf16x8;
typedef __attribute__((ext_vector_type(16))) float f32x16;

__device__ __forceinline__ void ld4(float d[4], const float* p) {
  const float4 v = *(const float4*)p; d[0]=v.x; d[1]=v.y; d[2]=v.z; d[3]=v.w;
}
__device__ __forceinline__ void st4(float* p, const float d[4]) {
  *(float4*)p = make_float4(d[0], d[1], d[2], d[3]);
}
__device__ __forceinline__ unsigned short bf_rne(float x) {
  unsigned b = __float_as_uint(x);
  unsigned r = b + 0x7FFFu + ((b >> 16) & 1u);
  return (unsigned short)(r >> 16);
}
__device__ __forceinline__ float bf2f(short v) {
  return __uint_as_float(((uint_t)(unsigned short)v) << 16);
}

// ---------------- kA: gates (softmax(logits/2)) and diag^2 ----------------
__global__ __launch_bounds__(64) void kA(const float* __restrict__ ctx,
    const float* __restrict__ GW, const float* __restrict__ Gb,
    const float* __restrict__ SgW, const float* __restrict__ Sgb,
    float* __restrict__ Wsm, float* __restrict__ Q2) {
  const int b = blockIdx.x, s = blockIdx.y, l = threadIdx.x;
  __shared__ float c[128];
  c[l]      = ctx[(size_t)b*128 + l];
  c[l + 64] = ctx[(size_t)b*128 + 64 + l];
  __syncthreads();
  if (l < 8) {
    float acc = Gb[s*8 + l];
    #pragma unroll 4
    for (int q = 0; q < 128; ++q) acc += c[q] * GW[(size_t)(s*128 + q)*8 + l];
    float li = acc * 0.5f;            // / TEMP (=2)
    float m = li;
    m = fmaxf(m, __shfl_xor(m, 1));
    m = fmaxf(m, __shfl_xor(m, 2));
    m = fmaxf(m, __shfl_xor(m, 4));
    float e = expf(li - m);
    float sum = e;
    sum += __shfl_xor(sum, 1);
    sum += __shfl_xor(sum, 2);
    sum += __shfl_xor(sum, 4);
    Wsm[((size_t)s*BSZ + b)*8 + l] = e / sum;
  } else if (l < 40) {
    const int d = l - 8;
    float acc = Sgb[s*32 + d];
    #pragma unroll 4
    for (int q = 0; q < 128; ++q) acc += c[q] * SgW[(size_t)(s*128 + q)*32 + d];
    float sp = fmaxf(acc, 0.f) + log1pf(expf(-fabsf(acc)));  // stable softplus
    float dg = fminf(sp, 1.0f);
    Q2[((size_t)s*BSZ + b)*32 + d] = dg * dg;
  }
}

// -------- kT: SWT[(s*1024+kc)*1024 + n] = M_{s,c,k}[(n&31)*32 + (n>>5)] ------
__global__ __launch_bounds__(256) void kT(const float* __restrict__ SW,
                                          float* __restrict__ SWT) {
  __shared__ float mt[1056];   // 32 rows x 33
  const int kc = blockIdx.x, s = blockIdx.y, t = threadIdx.x;
  const int k = kc >> 7, c = kc & 127;
  const float* src = SW + ((size_t)(s*128 + c))*8192 + (size_t)k*1024;
  float* dst = SWT + ((size_t)s*1024 + kc)*1024;
  for (int i = t; i < 1024; i += 256) mt[(i >> 5)*33 + (i & 31)] = src[i];
  __syncthreads();
  for (int i = t; i < 1024; i += 256) dst[i] = mt[(i & 31)*33 + (i >> 5)];
}

// -------- kCvtB: B'[s][n][kc] hi/lo bf16, coalesced (16-n groups) -----------
__global__ __launch_bounds__(256) void kCvtB(const float* __restrict__ SW,
    const float* __restrict__ SWT, const float* __restrict__ Sb,
    ushort_t* __restrict__ Bh, ushort_t* __restrict__ Bl) {
  const int s = blockIdx.y, t = threadIdx.x;
  const int n0 = blockIdx.x * 16;
  const int tn = t & 15, tck = t >> 4;
  const int n = n0 + tn;
  const int nT = (n & 31)*32 + (n >> 5);
  ushort_t* bh = Bh + (size_t)s*1114112;
  ushort_t* bl = Bl + (size_t)s*1114112;
  for (int kc0 = 0; kc0 < 1088; kc0 += 16) {
    const int kc = kc0 + tck;
    float v = 0.f;
    if (kc < 1024) {
      const int k = kc >> 7, c = kc & 127;
      v = SW[((size_t)(s*128 + c))*8192 + (size_t)k*1024 + n]
        - SWT[((size_t)s*1024 + kc)*1024 + n];
    } else if (kc < 1032) {
      const int k2 = kc - 1024;
      const float* base = Sb + (size_t)s*8192 + (size_t)k2*1024;
      v = base[n] - base[nT];
    }
    const unsigned short h = bf_rne(v);
    bh[(size_t)n*1088 + kc] = h;
    bl[(size_t)n*1088 + kc] = bf_rne(v - __uint_as_float(((unsigned)h) << 16));
  }
}

// -------- kCvtX: ctx -> hi/lo bf16 panels [4096][128] ----------------------
__global__ __launch_bounds__(256) void kCvtX(const float* __restrict__ ctx,
    ushort_t* __restrict__ Xh, ushort_t* __restrict__ Xl) {
  const int idx = blockIdx.x*256 + threadIdx.x;
  const float v = ctx[idx];
  const unsigned short h = bf_rne(v);
  Xh[idx] = h;
  Xl[idx] = bf_rne(v - __uint_as_float(((unsigned)h) << 16));
}

// -------- kCvtL: lwT[s][n][c] = L_W[s][c][n] hi/lo bf16 --------------------
__global__ __launch_bounds__(256) void kCvtL(const float* __restrict__ LW,
    ushort_t* __restrict__ Lh, ushort_t* __restrict__ Ll) {
  __shared__ float tile[32][33];
  const int nb = blockIdx.x * 32, cb = blockIdx.y * 32, s = blockIdx.z;
  const int tx = threadIdx.x & 31, ty = threadIdx.x >> 5;
  for (int r = ty; r < 32; r += 8)
    tile[r][tx] = LW[((size_t)(s*128 + cb + r))*2048 + nb + tx];
  __syncthreads();
  for (int r = ty; r < 32; r += 8) {
    const float v = tile[tx][r];          // LW[cb+tx][nb+r]
    const unsigned short h = bf_rne(v);
    const size_t o = ((size_t)s*2048 + nb + r)*128 + cb + tx;
    Lh[o] = h;
    Ll[o] = bf_rne(v - __uint_as_float(((unsigned)h) << 16));
  }
}

// -------- kCvtA: A'[b][kc] hi/lo bf16; kc<1024: w[k]*ctx[c]; 1024..1031: w ---
__global__ __launch_bounds__(256) void kCvtA(const float* __restrict__ ctx,
    const float* __restrict__ Wsm, ushort_t* __restrict__ Ah,
    ushort_t* __restrict__ Al, int s) {
  __shared__ float cs[128];
  __shared__ float wwv[8];
  const int b = blockIdx.x, t = threadIdx.x;
  if (t < 128) cs[t] = ctx[(size_t)b*128 + t];
  else if (t < 136) wwv[t - 128] = Wsm[((size_t)s*BSZ + b)*8 + (t - 128)];
  __syncthreads();
  for (int kc = t; kc < 1088; kc += 256) {
    float v = 0.f;
    if (kc < 1024) v = wwv[kc >> 7] * cs[kc & 127];
    else if (kc < 1032) v = wwv[kc - 1024];
    const unsigned short h = bf_rne(v);
    const float hf = __uint_as_float(((unsigned)h) << 16);
    Ah[(size_t)b*1088 + kc] = h;
    Al[(size_t)b*1088 + kc] = bf_rne(v - hf);
  }
}

// -------- kB3: AS_seg = A' @ B'^T via 32x32x16 bf16 MFMA, 3-product hi/lo ----
__global__ __launch_bounds__(256) void kB3(const ushort_t* __restrict__ Ah,
    const ushort_t* __restrict__ Al, const ushort_t* __restrict__ Bh,
    const ushort_t* __restrict__ Bl, float* __restrict__ ASseg) {
  __shared__ ushort_t sArr[2][2][8192];   // [buf][A/B][128 rows x 64 cols]
  const int t = threadIdx.x;
  const int l = t & 63, w = t >> 6;
  const int hh = l >> 5, lane31 = l & 31;
  const int nb = blockIdx.x * 128, bb = blockIdx.y * 128;
  const int wr0 = (w & 1) * 64, wc0 = (w >> 1) * 64;

  const ushort_t* APT[3] = {Ah, Ah, Al};
  const ushort_t* BPT[3] = {Bh, Bl, Bh};

  f32x16 acc[2][2];
  #pragma unroll
  for (int a = 0; a < 2; ++a)
    #pragma unroll
    for (int bq = 0; bq < 2; ++bq)
      #pragma unroll
      for (int e = 0; e < 16; ++e) acc[a][bq][e] = 0.f;

  #define STAGE(buf, it) do {                                                  \
    const int p_ = (it) / 17, ks_ = (it) - p_*17;                              \
    const ushort_t* As_ = APT[p_];                                             \
    const ushort_t* Bs_ = BPT[p_];                                             \
    _Pragma("unroll")                                                          \
    for (int i_ = 0; i_ < 4; ++i_) {                                           \
      const int gidx_ = i_*256 + t;                                            \
      const int r_ = gidx_ >> 3, g_ = gidx_ & 7;                               \
      const int gs_ = g_ ^ (r_ & 7);                                           \
      const ushort_t* srcA_ = As_ + (size_t)(bb + r_)*1088 + ks_*64 + gs_*8;   \
      const ushort_t* srcB_ = Bs_ + (size_t)(nb + r_)*1088 + ks_*64 + gs_*8;   \
      __builtin_amdgcn_global_load_lds(                                        \
        (const __attribute__((address_space(1))) unsigned int*)srcA_,          \
        (__attribute__((address_space(3))) unsigned int*)&sArr[buf][0][(i_*256 + w*64)*8], \
        16, 0, 0);                                                             \
      __builtin_amdgcn_global_load_lds(                                        \
        (const __attribute__((address_space(1))) unsigned int*)srcB_,          \
        (__attribute__((address_space(3))) unsigned int*)&sArr[buf][1][(i_*256 + w*64)*8], \
        16, 0, 0);                                                             \
    }                                                                          \
  } while (0)

  STAGE(0, 0);
  int cur = 0;
  #pragma unroll 1
  for (int it = 0; it < 51; ++it) {
    __syncthreads();                      // drain loads into buf[cur]
    if (it + 1 < 51) STAGE(cur ^ 1, it + 1);
    const ushort_t* lA = &sArr[cur][0][0];
    const ushort_t* lB = &sArr[cur][1][0];
    #pragma unroll
    for (int kc = 0; kc < 4; ++kc) {
      bf16x8 af[2], bfr[2];
      #pragma unroll
      for (int rt = 0; rt < 2; ++rt) {
        const int row = wr0 + rt*32 + lane31;
        const int slot = (kc*2 + hh) ^ (row & 7);
        af[rt] = *(const bf16x8*)&lA[row*64 + slot*8];
      }
      #pragma unroll
      for (int ct = 0; ct < 2; ++ct) {
        const int row = wc0 + ct*32 + lane31;
        const int slot = (kc*2 + hh) ^ (row & 7);
        bfr[ct] = *(const bf16x8*)&lB[row*64 + slot*8];
      }
      #pragma unroll
      for (int rt = 0; rt < 2; ++rt)
        #pragma unroll
        for (int ct = 0; ct < 2; ++ct)
          acc[rt][ct] = __builtin_amdgcn_mfma_f32_32x32x16_bf16(
              af[rt], bfr[ct], acc[rt][ct], 0, 0, 0);
    }
    cur ^= 1;
  }
  #undef STAGE

  #pragma unroll
  for (int rt = 0; rt < 2; ++rt)
    #pragma unroll
    for (int ct = 0; ct < 2; ++ct) {
      float* o = ASseg + ((size_t)(bb + wr0 + rt*32))*1024 + nb + wc0 + ct*32 + lane31;
      #pragma unroll
      for (int reg = 0; reg < 16; ++reg) {
        const int row = (reg & 3) + 8*(reg >> 2) + 4*hh;
        o[(size_t)row*1024] = acc[rt][ct][reg];
      }
    }
}

// -------- kL4: LtilT bf16 hi/lo panels [b][32 d][64 kr] via MFMA (K=128) ----
__global__ __launch_bounds__(256) void kL4(const ushort_t* __restrict__ Xh,
    const ushort_t* __restrict__ Xl, const ushort_t* __restrict__ Lh,
    const ushort_t* __restrict__ Ll, const float* __restrict__ Lb,
    const float* __restrict__ Wsm, ushort_t* __restrict__ LTh,
    ushort_t* __restrict__ LTl, int s) {
  __shared__ ushort_t sArr[2][2][8192];
  __shared__ float sqw[128][8];
  const int t = threadIdx.x;
  const int l = t & 63, w = t >> 6;
  const int hh = l >> 5, lane31 = l & 31;
  const int nb = blockIdx.x * 128, bb = blockIdx.y * 128;
  const int wr0 = (w & 1) * 64, wc0 = (w >> 1) * 64;
  for (int i = t; i < 1024; i += 256)
    sqw[i >> 3][i & 7] = sqrtf(Wsm[((size_t)s*BSZ + bb + (i >> 3))*8 + (i & 7)]);

  const ushort_t* APT[3] = {Xh, Xh, Xl};
  const ushort_t* BPT[3] = {Lh + (size_t)s*262144, Ll + (size_t)s*262144,
                            Lh + (size_t)s*262144};

  f32x16 acc[2][2];
  #pragma unroll
  for (int a = 0; a < 2; ++a)
    #pragma unroll
    for (int bq = 0; bq < 2; ++bq)
      #pragma unroll
      for (int e = 0; e < 16; ++e) acc[a][bq][e] = 0.f;

  #define STAGEL(buf, it) do {                                                 \
    const int p_ = (it) >> 1, ks_ = (it) & 1;                                  \
    const ushort_t* As_ = APT[p_];                                             \
    const ushort_t* Bs_ = BPT[p_];                                             \
    _Pragma("unroll")                                                          \
    for (int i_ = 0; i_ < 4; ++i_) {                                           \
      const int gidx_ = i_*256 + t;                                            \
      const int r_ = gidx_ >> 3, g_ = gidx_ & 7;                               \
      const int gs_ = g_ ^ (r_ & 7);                                           \
      const ushort_t* srcA_ = As_ + (size_t)(bb + r_)*128 + ks_*64 + gs_*8;    \
      const ushort_t* srcB_ = Bs_ + (size_t)(nb + r_)*128 + ks_*64 + gs_*8;    \
      __builtin_amdgcn_global_load_lds(                                        \
        (const __attribute__((address_space(1))) unsigned int*)srcA_,          \
        (__attribute__((address_space(3))) unsigned int*)&sArr[buf][0][(i_*256 + w*64)*8], \
        16, 0, 0);                                                             \
      __builtin_amdgcn_global_load_lds(                                        \
        (const __attribute__((address_space(1))) unsigned int*)srcB_,          \
        (__attribute__((address_space(3))) unsigned int*)&sArr[buf][1][(i_*256 + w*64)*8], \
        16, 0, 0);                                                             \
    }                                                                          \
  } while (0)

  STAGEL(0, 0);
  int cur = 0;
  #pragma unroll 1
  for (int it = 0; it < 6; ++it) {
    __syncthreads();
    if (it + 1 < 6) STAGEL(cur ^ 1, it + 1);
    const ushort_t* lA = &sArr[cur][0][0];
    const ushort_t* lB = &sArr[cur][1][0];
    #pragma unroll
    for (int kc = 0; kc < 4; ++kc) {
      bf16x8 af[2], bfr[2];
      #pragma unroll
      for (int rt = 0; rt < 2; ++rt) {
        const int row = wr0 + rt*32 + lane31;
        const int slot = (kc*2 + hh) ^ (row & 7);
        af[rt] = *(const bf16x8*)&lA[row*64 + slot*8];
      }
      #pragma unroll
      for (int ct = 0; ct < 2; ++ct) {
        const int row = wc0 + ct*32 + lane31;
        const int slot = (kc*2 + hh) ^ (row & 7);
        bfr[ct] = *(const bf16x8*)&lB[row*64 + slot*8];
      }
      #pragma unroll
      for (int rt = 0; rt < 2; ++rt)
        #pragma unroll
        for (int ct = 0; ct < 2; ++ct)
          acc[rt][ct] = __builtin_amdgcn_mfma_f32_32x32x16_bf16(
              af[rt], bfr[ct], acc[rt][ct], 0, 0, 0);
    }
    cur ^= 1;
  }
  #undef STAGEL

  // epilogue: v=(acc+Lb[n])*sqrt(w[b][k]); LtilT[b][d][kr=k*8+r] hi/lo bf16
  #pragma unroll
  for (int rt = 0; rt < 2; ++rt)
    #pragma unroll
    for (int ct = 0; ct < 2; ++ct) {
      const int n = nb + wc0 + ct*32 + lane31;   // n = k*256 + d*8 + r
      const float lb = Lb[(size_t)s*2048 + n];
      const int kidx = n >> 8;
      const int d = (n >> 3) & 31, r = n & 7;
      const size_t coloff = (size_t)d*64 + kidx*8 + r;
      #pragma unroll
      for (int reg = 0; reg < 16; ++reg) {
        const int lrow = wr0 + rt*32 + (reg & 3) + 8*(reg >> 2) + 4*hh;
        const float v = (acc[rt][ct][reg] + lb) * sqw[lrow][kidx];
        const unsigned short h = bf_rne(v);
        const size_t o = (size_t)(bb + lrow)*2048 + coloff;
        LTh[o] = h;
        LTl[o] = bf_rne(v - __uint_as_float(((unsigned)h) << 16));
      }
    }
}

// ================= kC14: per-seg MFMA expm + propagation, LLT folded ==========
struct Frag { bf16x8 h0, l0, h1, l1; };

__device__ __forceinline__ void cvt8(const float x[8], bf16x8& hi, bf16x8& lo) {
  uint_t h[4], l[4];
  #pragma unroll
  for (int p = 0; p < 4; ++p) {
    const uint_t b0 = __float_as_uint(x[2*p]);
    const uint_t b1 = __float_as_uint(x[2*p + 1]);
    h[p] = __builtin_amdgcn_perm(b1, b0, 0x07060302u);
    const float l0f = x[2*p]     - __uint_as_float(b0 & 0xFFFF0000u);  // exact
    const float l1f = x[2*p + 1] - __uint_as_float(b1 & 0xFFFF0000u);  // exact
    l[p] = __builtin_amdgcn_perm(__float_as_uint(l1f), __float_as_uint(l0f),
                                 0x07060302u);
  }
  hi = __builtin_bit_cast(bf16x8, make_uint4(h[0], h[1], h[2], h[3]));
  lo = __builtin_bit_cast(bf16x8, make_uint4(l[0], l[1], l[2], l[3]));
}
__device__ __forceinline__ void rd_row8(const float* M, int r, int kb, float o[8]) {
  const float* p = M + r*32;
  ld4(o,     p + ((kb)     ^ XRS(r)));
  ld4(o + 4, p + ((kb + 4) ^ XRS(r)));
}
__device__ __forceinline__ void rd_col8(const float* M, int c, int kb, float o[8]) {
  #pragma unroll
  for (int e = 0; e < 8; ++e) o[e] = M[(kb + e)*32 + (c ^ XRS(kb + e))];
}
__device__ __forceinline__ void mkfrag_row(const float* M, int r, int hoff, Frag& f) {
  float t0[8], t1[8];
  rd_row8(M, r, hoff, t0);
  rd_row8(M, r, 16 + hoff, t1);
  cvt8(t0, f.h0, f.l0);
  cvt8(t1, f.h1, f.l1);
}
__device__ __forceinline__ void mkfrag_col(const float* M, int c, int hoff, Frag& f) {
  float t0[8], t1[8];
  rd_col8(M, c, hoff, t0);
  rd_col8(M, c, 16 + hoff, t1);
  cvt8(t0, f.h0, f.l0);
  cvt8(t1, f.h1, f.l1);
}
__device__ __forceinline__ f32x16 mmacc(const Frag& A, const Frag& B, f32x16 acc) {
  acc = __builtin_amdgcn_mfma_f32_32x32x16_bf16(A.h0, B.h0, acc, 0, 0, 0);
  acc = __builtin_amdgcn_mfma_f32_32x32x16_bf16(A.h0, B.l0, acc, 0, 0, 0);
  acc = __builtin_amdgcn_mfma_f32_32x32x16_bf16(A.l0, B.h0, acc, 0, 0, 0);
  acc = __builtin_amdgcn_mfma_f32_32x32x16_bf16(A.h1, B.h1, acc, 0, 0, 0);
  acc = __builtin_amdgcn_mfma_f32_32x32x16_bf16(A.h1, B.l1, acc, 0, 0, 0);
  acc = __builtin_amdgcn_mfma_f32_32x32x16_bf16(A.l1, B.h1, acc, 0, 0, 0);
  return acc;
}
__device__ __forceinline__ f32x16 zero16() {
  f32x16 z = {0.f,0.f,0.f,0.f,0.f,0.f,0.f,0.f,0.f,0.f,0.f,0.f,0.f,0.f,0.f,0.f};
  return z;
}
__device__ __forceinline__ void st_T(float* M, int j, int ho4, const float v[16]) {
  float* p = M + j*32;
  #pragma unroll
  for (int m = 0; m < 4; ++m) st4(p + ((8*m + ho4) ^ XRS(j)), v + 4*m);
}
__device__ __forceinline__ void ld16_T(const float* M, int j, int ho4, float o[16]) {
  const float* p = M + j*32;
  #pragma unroll
  for (int m = 0; m < 4; ++m) ld4(o + 4*m, p + ((8*m + ho4) ^ XRS(j)));
}

__global__ __launch_bounds__(64, 3) void kC14(const float* __restrict__ AS,
    const float* __restrict__ Q2, const float* __restrict__ z0,
    const ushort_t* __restrict__ LTh, const ushort_t* __restrict__ LTl,
    float* __restrict__ out, int s) {
  __shared__ float S11[1024];  // R11^T (Phi^T) ; H^T scratch in propagation
  __shared__ float S12[1024];  // a staging; R12^T (E12^T); cov buffer
  __shared__ float S22[1024];  // R22^T ; later Qd
  __shared__ float zarr[32], qds[32];
  const int b = blockIdx.x, t = threadIdx.x;
  const int j = t & 31, hh = t >> 5;
  const int hoff = hh * 8, ho4 = hh * 4;

  float* covout = out + 3145728 + (size_t)b*24576;
  float* stout  = out + (size_t)b*768;

  // ---- state init: z, cov (chained through the output buffer) ----
  if (t < 32) {
    zarr[t] = (s == 0) ? z0[(size_t)b*32 + t] : stout[(8*s - 1)*32 + t];
    qds[t] = Q2[((size_t)s*BSZ + b)*32 + t] * XSC;
  }
  float covreg[16];
  if (s == 0) {
    #pragma unroll
    for (int r = 0; r < 16; ++r) covreg[r] = 0.f;
  } else {
    const float* cbp = covout + (size_t)(8*s - 1)*1024;
    #pragma unroll
    for (int r = 0; r < 16; ++r)
      covreg[r] = cbp[((r&3) + 8*(r>>2) + ho4)*32 + j];
  }

  // ---- LLT = LtilT @ LtilT^T via MFMA (A-frag == B-frag, K=64) ----
  f32x16 llt = zero16();
  {
    const ushort_t* ph = LTh + (size_t)b*2048 + j*64 + hoff;
    const ushort_t* pl = LTl + (size_t)b*2048 + j*64 + hoff;
    Frag FA, FB;
    FA.h0 = *(const bf16x8*)&ph[0];  FA.l0 = *(const bf16x8*)&pl[0];
    FA.h1 = *(const bf16x8*)&ph[16]; FA.l1 = *(const bf16x8*)&pl[16];
    FB.h0 = *(const bf16x8*)&ph[32]; FB.l0 = *(const bf16x8*)&pl[32];
    FB.h1 = *(const bf16x8*)&ph[48]; FB.l1 = *(const bf16x8*)&pl[48];
    llt = mmacc(FA, FA, llt);
    llt = mmacc(FB, FB, llt);
  }

  // ---- A tile (pattern [j][8m+ho4+e]), -LLT, -muI, frob clamp, scale -------
  const float* asb = AS + ((size_t)s*BSZ + b)*1024;
  float av[16];
  #pragma unroll
  for (int m = 0; m < 4; ++m) ld4(av + 4*m, &asb[j*32 + 8*m + ho4]);
  #pragma unroll
  for (int r = 0; r < 16; ++r) {
    av[r] -= llt[r];                    // LLT[col(r)][j] == LLT[j][col(r)]
    const int col = (r & 3) + 8*(r >> 2) + ho4;
    if (col == j) av[r] -= MUC;
  }
  float ssq = 0.f;
  #pragma unroll
  for (int r = 0; r < 16; ++r) ssq += av[r]*av[r];
  #pragma unroll
  for (int off = 1; off < 64; off <<= 1) ssq += __shfl_xor(ssq, off);
  const float frob = sqrtf(ssq);
  const float sc = (frob > 3.0f ? 3.0f / (frob + 1e-6f) : 1.0f) * XSC;
  #pragma unroll
  for (int r = 0; r < 16; ++r) av[r] *= sc;
  __syncthreads();
  #pragma unroll
  for (int m = 0; m < 4; ++m)
    st4(&S12[j*32 + ((8*m + ho4) ^ XRS(j))], av + 4*m);  // S12 = a (row j)
  __syncthreads();
  Frag aA, aT;
  mkfrag_row(S12, j, hoff, aA);   // A-frag of a
  mkfrag_col(S12, j, hoff, aT);   // A-frag of a^T
  __syncthreads();
  #pragma unroll
  for (int m = 0; m < 4; ++m) {
    float id[4], zo[4] = {0.f, 0.f, 0.f, 0.f};
    #pragma unroll
    for (int e = 0; e < 4; ++e) id[e] = (16*hh + 4*m + e == j) ? 1.f : 0.f;
    st4(&S11[j*32 + ((16*hh + 4*m) ^ XRS(j))], id);
    st4(&S22[j*32 + ((16*hh + 4*m) ^ XRS(j))], id);
    st4(&S12[j*32 + ((16*hh + 4*m) ^ XRS(j))], zo);
  }
  __syncthreads();
  float qv[16];
  #pragma unroll
  for (int r = 0; r < 16; ++r) qv[r] = qds[(r&3) + 8*(r>>2) + ho4];

  // ---- Taylor Horner ORDER=4 on X=[[a,q],[0,-a^T]] (transposed blocks) ----
  for (int k = 4; k >= 1; --k) {
    const float rk = 1.0f / (float)k;
    Frag Bf;
    float Xs[16];
    mkfrag_row(S11, j, hoff, Bf);
    f32x16 X = mmacc(aA, Bf, zero16());
    #pragma unroll
    for (int r = 0; r < 16; ++r) {
      const int row = (r&3) + 8*(r>>2) + ho4;
      Xs[r] = X[r]*rk + (row == j ? 1.f : 0.f);
    }
    st_T(S11, j, ho4, Xs);
    mkfrag_row(S12, j, hoff, Bf);
    X = mmacc(aA, Bf, zero16());
    float rv[16];
    ld16_T(S22, j, ho4, rv);
    #pragma unroll
    for (int r = 0; r < 16; ++r) Xs[r] = (X[r] + qv[r]*rv[r]) * rk;
    st_T(S12, j, ho4, Xs);
    mkfrag_row(S22, j, hoff, Bf);
    X = mmacc(aT, Bf, zero16());
    #pragma unroll
    for (int r = 0; r < 16; ++r) {
      const int row = (r&3) + 8*(r>>2) + ho4;
      Xs[r] = (row == j ? 1.f : 0.f) - X[r]*rk;
    }
    st_T(S22, j, ho4, Xs);
  }
  __syncthreads();

  // ---- squaring 0 ----
  {
    Frag Ac, Br;
    float Xs[16];
    mkfrag_col(S11, j, hoff, Ac);
    mkfrag_row(S11, j, hoff, Br);
    f32x16 X1 = mmacc(Ac, Br, zero16());
    #pragma unroll
    for (int r = 0; r < 16; ++r) Xs[r] = X1[r];
    st_T(S11, j, ho4, Xs);
    Frag B12; mkfrag_row(S12, j, hoff, B12);
    f32x16 X2 = mmacc(Ac, B12, zero16());
    Frag A12; mkfrag_col(S12, j, hoff, A12);
    Frag B22; mkfrag_row(S22, j, hoff, B22);
    X2 = mmacc(A12, B22, X2);
    #pragma unroll
    for (int r = 0; r < 16; ++r) Xs[r] = X2[r];
    st_T(S12, j, ho4, Xs);
    Frag A22; mkfrag_col(S22, j, hoff, A22);
    f32x16 X3 = mmacc(A22, B22, zero16());
    #pragma unroll
    for (int r = 0; r < 16; ++r) Xs[r] = X3[r];
    st_T(S22, j, ho4, Xs);
  }
  __syncthreads();
  // ---- squaring 1: R11, R12 only ----
  {
    Frag Ac, Br;
    float Xs[16];
    mkfrag_col(S11, j, hoff, Ac);
    mkfrag_row(S11, j, hoff, Br);
    f32x16 X1 = mmacc(Ac, Br, zero16());
    Frag B12; mkfrag_row(S12, j, hoff, B12);
    f32x16 X2 = mmacc(Ac, B12, zero16());
    Frag A12; mkfrag_col(S12, j, hoff, A12);
    Frag B22; mkfrag_row(S22, j, hoff, B22);
    X2 = mmacc(A12, B22, X2);
    #pragma unroll
    for (int r = 0; r < 16; ++r) Xs[r] = X1[r];
    st_T(S11, j, ho4, Xs);
    #pragma unroll
    for (int r = 0; r < 16; ++r) Xs[r] = X2[r];
    st_T(S12, j, ho4, Xs);
  }
  __syncthreads();

  // ---- Qd = 0.5*(Phi@E12 + (Phi@E12)^T) -> S22 ----
  Frag PhiF;
  mkfrag_col(S11, j, hoff, PhiF);
  {
    Frag B12; mkfrag_row(S12, j, hoff, B12);
    f32x16 Xq = mmacc(PhiF, B12, zero16());
    float Xs[16];
    #pragma unroll
    for (int r = 0; r < 16; ++r) Xs[r] = Xq[r];
    st_T(S22, j, ho4, Xs);
    __syncthreads();
    float sym[16];
    #pragma unroll
    for (int r = 0; r < 16; ++r) {
      const int row = (r&3) + 8*(r>>2) + ho4;
      const float tv = S22[row*32 + (j ^ XRS(row))];
      sym[r] = 0.5f * (Xs[r] + tv);
    }
    __syncthreads();
    st_T(S22, j, ho4, sym);
  }
  __syncthreads();

  // ---- stage cov (covreg, C/D order) into S12 (E12 dead); hoist Qd frag ----
  st_T(S12, j, ho4, covreg);
  float qdr[16];
  ld16_T(S22, j, ho4, qdr);          // loop-invariant: Qd[row(r)][j]
  __syncthreads();

  // ---- 8 propagation steps: H = cov@Phi^T ; cov' = Phi@H + Qd ; z = Phi z --
  // Both frag builds are ROW reads: cov symmetric -> A-frag = rows(S12);
  // st_T(H) makes S11 = H^T row-major -> B-frag of MM(Phi,H^T rows) = Phi@H.
  for (int tt = 0; tt < 8; ++tt) {
    Frag Acov; mkfrag_row(S12, j, hoff, Acov);
    f32x16 H = mmacc(Acov, PhiF, zero16());        // H = cov @ Phi^T
    float Hs[16];
    #pragma unroll
    for (int r = 0; r < 16; ++r) Hs[r] = H[r];
    st_T(S11, j, ho4, Hs);                         // S11 = H^T (Phi in regs)
    Frag BH; mkfrag_row(S11, j, hoff, BH);
    f32x16 C = mmacc(PhiF, BH, zero16());          // cov' = Phi @ H
    float Cs[16];
    #pragma unroll
    for (int r = 0; r < 16; ++r) Cs[r] = C[r] + qdr[r];
    float zp = 0.f;
    #pragma unroll
    for (int e = 0; e < 8; ++e) {
      zp += (bf2f(PhiF.h0[e]) + bf2f(PhiF.l0[e])) * zarr[hoff + e];
      zp += (bf2f(PhiF.h1[e]) + bf2f(PhiF.l1[e])) * zarr[16 + hoff + e];
    }
    zp += __shfl_xor(zp, 32);
    st_T(S12, j, ho4, Cs);
    float* cb = covout + (size_t)(s*8 + tt)*1024;
    #pragma unroll
    for (int r = 0; r < 16; ++r)
      cb[((r&3) + 8*(r>>2) + ho4)*32 + j] = Cs[r];
    if (t < 32) {
      zarr[t] = zp;
      stout[(s*8 + tt)*32 + t] = zp;
    }
    __syncthreads();
  }
}

// ---------------- launch ----------------
extern "C" void kernel_launch(void* const* d_in, const int* in_sizes, int n_in,
                              void* d_out, int out_size, void* d_ws, size_t ws_size,
                              hipStream_t stream) {
  const float* ctx  = (const float*)d_in[0];
  const float* z0   = (const float*)d_in[1];
  const float* S_W  = (const float*)d_in[2];
  const float* S_b  = (const float*)d_in[3];
  const float* L_W  = (const float*)d_in[4];
  const float* L_b  = (const float*)d_in[5];
  const float* G_W  = (const float*)d_in[6];
  const float* G_b  = (const float*)d_in[7];
  const float* Sg_W = (const float*)d_in[8];
  const float* Sg_b = (const float*)d_in[9];
  float* out = (float*)d_out;
  float* ws  = (float*)d_ws;

  // ws layout (f32 offsets): same as R14 (93.2 MB peak)
  float* w_   = ws;
  float* q2   = ws + 98304;
  float* as_  = ws + 1015808;
  float* swt  = ws + 1015808;          // aliases as_ head; dead before kB3
  ushort_t* panAh  = (ushort_t*)(ws + 13598720);
  ushort_t* panAl  = panAh + 4456448;
  ushort_t* panBh3 = panAl + 4456448;
  ushort_t* panBl3 = panBh3 + 3342336;
  ushort_t* LTh = (ushort_t*)(ws + 13598720);   // aliases A/B panels (post-kB3)
  ushort_t* LTl = LTh + 8388608;
  ushort_t* cxh = (ushort_t*)(ws + 21987328);
  ushort_t* cxl = cxh + 524288;
  ushort_t* lwh = cxl + 524288;
  ushort_t* lwl = lwh + 786432;

  kA   <<<dim3(4096, 3), 64,  0, stream>>>(ctx, G_W, G_b, Sg_W, Sg_b, w_, q2);
  kCvtX<<<dim3(2048),    256, 0, stream>>>(ctx, cxh, cxl);
  kCvtL<<<dim3(64, 4, 3),256, 0, stream>>>(L_W, lwh, lwl);
  kT   <<<dim3(1024, 3), 256, 0, stream>>>(S_W, swt);
  kCvtB<<<dim3(64, 3),   256, 0, stream>>>(S_W, swt, S_b, panBh3, panBl3);
  for (int s = 0; s < 3; ++s) {
    kCvtA<<<dim3(4096), 256, 0, stream>>>(ctx, w_, panAh, panAl, s);
    kB3  <<<dim3(8, 32), 256, 0, stream>>>(panAh, panAl,
                                           panBh3 + (size_t)s*1114112,
                                           panBl3 + (size_t)s*1114112,
                                           as_ + (size_t)s*4194304);
  }
  for (int s = 0; s < 3; ++s) {
    kL4 <<<dim3(16, 32), 256, 0, stream>>>(cxh, cxl, lwh, lwl, L_b, w_,
                                           LTh, LTl, s);
    kC14<<<dim3(4096),   64,  0, stream>>>(as_, q2, z0, LTh, LTl, out, s);
  }
}